// Round 11
// baseline (287.841 us; speedup 1.0000x reference)
//
#include <hip/hip_runtime.h>
#include <math.h>

#define NB 128     // batch
#define NC 64      // channels
#define NT 128     // segment length
#define HIDN 128   // hidden
#define NE 64      // attn embed
#define NHD 4      // heads
#define HD 16      // head dim

// ---------------------------------------------------------------------------
// 1. Analytic signal (unchanged; bit-identical math; [b][c][t] layout).
// ---------------------------------------------------------------------------
__global__ void analytic_kernel(const float* __restrict__ eeg,
                                float* __restrict__ re, float* __restrict__ im) {
    int row = blockIdx.x;            // b*NC + c
    int t = threadIdx.x;             // 0..127
    __shared__ float xs[NT];
    __shared__ double cotv[64];
    xs[t] = eeg[row * NT + t];
    if (t < 64) {
        double d = (double)(2 * t + 1);
        double a = 3.14159265358979323846 * d / 128.0;
        cotv[t] = cos(a) / sin(a);
    }
    __syncthreads();
    double ar = 0.0, ai = 0.0;
    #pragma unroll
    for (int m = 0; m < 64; ++m) {
        int d = 2 * m + 1;
        int s = (t - d) & 127;
        double xv = (double)xs[s];
        ar += xv;
        ai += cotv[m] * xv;
    }
    double rr = (double)xs[t] + ar * (1.0 / 64.0);
    double ii = ai * (1.0 / 64.0);
    re[row * NT + t] = (float)rr;
    im[row * NT + t] = (float)ii;
}

// ---------------------------------------------------------------------------
// 2. PLI v3 (unchanged). Bit-identical accumulation.
// ---------------------------------------------------------------------------
__global__ void pli_kernel(const float* __restrict__ re, const float* __restrict__ im,
                           float* __restrict__ wpli, float* __restrict__ deg) {
    int b = blockIdx.x >> 4;
    int i0 = (blockIdx.x & 15) << 2;
    int tid = threadIdx.x;           // 256
    int w = tid >> 6;
    int j = tid & 63;
    __shared__ float4 sre4[64 * 32];
    __shared__ float4 sim4[64 * 32];
    __shared__ int pacc[4][4][64];
    const float* reb = re + b * (NC * NT);
    const float* imb = im + b * (NC * NT);
    for (int idx4 = tid; idx4 < 2048; idx4 += 256) {
        int c = idx4 >> 5, t4 = idx4 & 31;
        int slot = c * 32 + (t4 ^ (c & 31));
        sre4[slot] = ((const float4*)reb)[idx4];
        sim4[slot] = ((const float4*)imb)[idx4];
    }
    __syncthreads();
    int acc0 = 0, acc1 = 0, acc2 = 0, acc3 = 0;
    #pragma unroll
    for (int tt = 0; tt < 8; ++tt) {
        int t4 = w * 8 + tt;
        float4 rj = sre4[j * 32 + (t4 ^ (j & 31))];
        float4 ij = sim4[j * 32 + (t4 ^ (j & 31))];
        #pragma unroll
        for (int di = 0; di < 4; ++di) {
            int i = i0 + di;
            float4 ri = sre4[i * 32 + (t4 ^ (i & 31))];
            float4 ii = sim4[i * 32 + (t4 ^ (i & 31))];
            float c0 = ii.x * rj.x - ri.x * ij.x;
            float c1 = ii.y * rj.y - ri.y * ij.y;
            float c2 = ii.z * rj.z - ri.z * ij.z;
            float c3 = ii.w * rj.w - ri.w * ij.w;
            int d = ((c0 > 0.f) ? 1 : ((c0 < 0.f) ? -1 : 0))
                  + ((c1 > 0.f) ? 1 : ((c1 < 0.f) ? -1 : 0))
                  + ((c2 > 0.f) ? 1 : ((c2 < 0.f) ? -1 : 0))
                  + ((c3 > 0.f) ? 1 : ((c3 < 0.f) ? -1 : 0));
            if (di == 0) acc0 += d;
            else if (di == 1) acc1 += d;
            else if (di == 2) acc2 += d;
            else acc3 += d;
        }
    }
    pacc[w][0][j] = acc0; pacc[w][1][j] = acc1;
    pacc[w][2][j] = acc2; pacc[w][3][j] = acc3;
    __syncthreads();
    int di2 = tid >> 6, j2 = tid & 63;
    int a = pacc[0][di2][j2] + pacc[1][di2][j2] + pacc[2][di2][j2] + pacc[3][di2][j2];
    float p = fabsf((float)a * (1.f / (float)NT));
    int i = i0 + di2;
    if (j2 == i) p = 0.f;
    wpli[b * (NC * NC) + i * NC + j2] = p;
    float s = p;
    #pragma unroll
    for (int off = 32; off > 0; off >>= 1) s += __shfl_down(s, off);
    if (j2 == 0) deg[b * NC + i] = s;
}

// ---------------------------------------------------------------------------
// Device-scope grid barrier (R8-verified). Grid 256 x 1 block/CU -> all
// resident. Counter reset by hipMemsetAsync each launch.
// ---------------------------------------------------------------------------
__device__ __forceinline__ void grid_bar(int* bar, int nblk) {
    __threadfence();
    __syncthreads();
    if (threadIdx.x == 0) {
        __hip_atomic_fetch_add(bar, 1, __ATOMIC_ACQ_REL, __HIP_MEMORY_SCOPE_AGENT);
        while (__hip_atomic_load(bar, __ATOMIC_ACQUIRE, __HIP_MEMORY_SCOPE_AGENT) < nblk)
            __builtin_amdgcn_s_sleep(8);
    }
    __syncthreads();
    __threadfence();
}

// ---------------------------------------------------------------------------
// 3. GCN layer 1 + [grid barrier] + GCN layer 2, one kernel.
//    256 blocks (b, half) x 1024 threads; ~142 KB LDS -> 1 block/CU, all
//    resident. Per-phase math identical to R10's gcn_fused<128,false> and
//    gcn_fused<64,true>; arow staged once for both phases.
// ---------------------------------------------------------------------------
__global__ __launch_bounds__(1024, 1) void gcn12(
        const float* __restrict__ adj, const float* __restrict__ deg,
        const float* __restrict__ eeg,
        const float* __restrict__ g1w, const float* __restrict__ g1b,
        const float* __restrict__ g2w, const float* __restrict__ g2b,
        const float* __restrict__ bn1g, const float* __restrict__ bn1b,
        float* __restrict__ w_x1, float* __restrict__ w_x2,
        double* __restrict__ dpart1, double* __restrict__ dpart2,
        int* __restrict__ bar) {
    int b = blockIdx.x >> 1;
    int half = blockIdx.x & 1;
    int tid = threadIdx.x;           // 1024
    __shared__ float dn_s[64];
    __shared__ float stat_s[64][2];
    __shared__ float arow[32][68];
    __shared__ float xs[64][128];
    __shared__ float sup[32][132];
    __shared__ float WsT[128][132];
    __shared__ double dred[16][64][2];

    if (tid < 64)
        dn_s[tid] = (float)(1.0 / sqrt((double)deg[b * 64 + tid] + 1e-8));
    __syncthreads();
    // stage arow (this half's 32 rows) — persists across both phases
    if (tid < 512) {
        int il = tid >> 4, j4 = tid & 15;
        int i = half * 32 + il;
        float4 v = *(const float4*)&adj[b * 4096 + i * 64 + j4 * 4];
        float di = dn_s[i];
        v.x *= di * dn_s[j4 * 4 + 0];
        v.y *= di * dn_s[j4 * 4 + 1];
        v.z *= di * dn_s[j4 * 4 + 2];
        v.w *= di * dn_s[j4 * 4 + 3];
        *(float4*)&arow[il][j4 * 4] = v;
    }
    // ---------------- phase 1: GCN1 (IN=eeg, OUT=128) ----------------
    #pragma unroll
    for (int p = 0; p < 2; ++p) {
        int idx4 = tid + p * 1024;
        int r = idx4 >> 5, c4 = idx4 & 31;
        float4 v = ((const float4*)(eeg + b * 8192))[idx4];
        *(float4*)&xs[r][c4 * 4] = v;
    }
    #pragma unroll
    for (int p = 0; p < 4; ++p) {    // W1^T [k][o], 128 cols
        int idx4 = tid + p * 1024;
        int o = idx4 & 127, k4 = idx4 >> 7;
        float4 w = *(const float4*)&g1w[o * 128 + k4 * 4];
        WsT[k4 * 4 + 0][o] = w.x;
        WsT[k4 * 4 + 1][o] = w.y;
        WsT[k4 * 4 + 2][o] = w.z;
        WsT[k4 * 4 + 3][o] = w.w;
    }
    __syncthreads();
    int il = tid >> 5;
    int i = half * 32 + il;
    {
        int f0 = (tid & 31) * 4;
        float a0 = 0.f, a1 = 0.f, a2 = 0.f, a3 = 0.f;
        #pragma unroll 8
        for (int j = 0; j < 64; ++j) {
            float a = arow[il][j];
            float4 xv = *(const float4*)&xs[j][f0];
            a0 += a * xv.x; a1 += a * xv.y; a2 += a * xv.z; a3 += a * xv.w;
        }
        *(float4*)&sup[il][f0] = make_float4(a0, a1, a2, a3);
    }
    __syncthreads();
    {
        int o0 = (tid & 31) * 4;
        float c[4] = {};
        #pragma unroll 8
        for (int k = 0; k < 128; ++k) {
            float s = sup[il][k];
            float4 w0 = *(const float4*)&WsT[k][o0];
            c[0] += s * w0.x; c[1] += s * w0.y; c[2] += s * w0.z; c[3] += s * w0.w;
        }
        float4 r0 = make_float4(c[0] + g1b[o0], c[1] + g1b[o0 + 1],
                                c[2] + g1b[o0 + 2], c[3] + g1b[o0 + 3]);
        *(float4*)&w_x1[b * 8192 + i * 128 + o0] = r0;
        double ds  = (double)r0.x + (double)r0.y + (double)r0.z + (double)r0.w;
        double ds2 = (double)r0.x * r0.x + (double)r0.y * r0.y
                   + (double)r0.z * r0.z + (double)r0.w * r0.w;
        #pragma unroll
        for (int off = 16; off > 0; off >>= 1) {
            ds  += __shfl_down(ds, off, 32);
            ds2 += __shfl_down(ds2, off, 32);
        }
        if ((tid & 31) == 0) {
            dpart1[(b * 64 + i) * 2]     = ds;
            dpart1[(b * 64 + i) * 2 + 1] = ds2;
        }
    }
    grid_bar(bar, NB * 2);
    // ---------------- phase 2: GCN2 (IN=BN1(x1), OUT=64) ----------------
    {
        int c = tid & 63, chunk = tid >> 6;
        double s = 0.0, s2 = 0.0;
        for (int bi = chunk * 8; bi < chunk * 8 + 8; ++bi) {
            s  += dpart1[(bi * 64 + c) * 2];
            s2 += dpart1[(bi * 64 + c) * 2 + 1];
        }
        dred[chunk][c][0] = s;
        dred[chunk][c][1] = s2;
    }
    __syncthreads();
    if (tid < 64) {
        double s = 0.0, s2 = 0.0;
        for (int ch = 0; ch < 16; ++ch) {
            s  += dred[ch][tid][0];
            s2 += dred[ch][tid][1];
        }
        double N = (double)(NB * HIDN);
        double m = s / N;
        double var = s2 / N - m * m;
        stat_s[tid][0] = (float)m;
        stat_s[tid][1] = (float)(1.0 / sqrt(var + 1e-5));
    }
    __syncthreads();
    #pragma unroll
    for (int p = 0; p < 2; ++p) {    // stage BN1+ReLU(x1)
        int idx4 = tid + p * 1024;
        int r = idx4 >> 5, c4 = idx4 & 31;
        float4 v = ((const float4*)(w_x1 + b * 8192))[idx4];
        float m = stat_s[r][0], rs = stat_s[r][1], gg = bn1g[r], bv = bn1b[r];
        v.x = (v.x - m) * rs * gg + bv; v.x = v.x > 0.f ? v.x : 0.f;
        v.y = (v.y - m) * rs * gg + bv; v.y = v.y > 0.f ? v.y : 0.f;
        v.z = (v.z - m) * rs * gg + bv; v.z = v.z > 0.f ? v.z : 0.f;
        v.w = (v.w - m) * rs * gg + bv; v.w = v.w > 0.f ? v.w : 0.f;
        *(float4*)&xs[r][c4 * 4] = v;
    }
    #pragma unroll
    for (int p = 0; p < 2; ++p) {    // W2^T [k][o], 64 cols
        int idx4 = tid + p * 1024;
        int o = idx4 & 63, k4 = idx4 >> 6;
        float4 w = *(const float4*)&g2w[o * 128 + k4 * 4];
        WsT[k4 * 4 + 0][o] = w.x;
        WsT[k4 * 4 + 1][o] = w.y;
        WsT[k4 * 4 + 2][o] = w.z;
        WsT[k4 * 4 + 3][o] = w.w;
    }
    __syncthreads();
    {
        int f0 = (tid & 31) * 4;
        float a0 = 0.f, a1 = 0.f, a2 = 0.f, a3 = 0.f;
        #pragma unroll 8
        for (int j = 0; j < 64; ++j) {
            float a = arow[il][j];
            float4 xv = *(const float4*)&xs[j][f0];
            a0 += a * xv.x; a1 += a * xv.y; a2 += a * xv.z; a3 += a * xv.w;
        }
        *(float4*)&sup[il][f0] = make_float4(a0, a1, a2, a3);
    }
    __syncthreads();
    {
        int o0 = (tid & 31) * 2;
        float c0 = 0.f, c1 = 0.f;
        #pragma unroll 8
        for (int k = 0; k < 128; ++k) {
            float s = sup[il][k];
            c0 += s * WsT[k][o0];
            c1 += s * WsT[k][o0 + 1];
        }
        c0 += g2b[o0];
        c1 += g2b[o0 + 1];
        *(float2*)&w_x2[b * 4096 + i * 64 + o0] = make_float2(c0, c1);
        double ds  = (double)c0 + (double)c1;
        double ds2 = (double)c0 * c0 + (double)c1 * c1;
        #pragma unroll
        for (int off = 16; off > 0; off >>= 1) {
            ds  += __shfl_down(ds, off, 32);
            ds2 += __shfl_down(ds2, off, 32);
        }
        if ((tid & 31) == 0) {
            dpart2[(b * 64 + i) * 2]     = ds;
            dpart2[(b * 64 + i) * 2 + 1] = ds2;
        }
    }
}

// ---------------------------------------------------------------------------
// 4. Attention per (b, head) + deterministic folded out-projection.
//    Identical math to R10 attn_head; the 4th-arriving block of each b
//    (any identity — result order-independent) computes feat[b].
// ---------------------------------------------------------------------------
__global__ __launch_bounds__(256) void attn_head(
        const float* __restrict__ x2, const double* __restrict__ dpart2,
        const float* __restrict__ g, const float* __restrict__ bb,
        const float* __restrict__ Win, const float* __restrict__ bin,
        const float* __restrict__ Wout, const float* __restrict__ bout,
        float* __restrict__ w_mo, int* __restrict__ cnt,
        float* __restrict__ feat) {
    int b = blockIdx.x >> 2, h = blockIdx.x & 3;
    int tid = threadIdx.x;
    int lane = tid & 63, wv = tid >> 6;
    __shared__ double dred[4][64][2];
    __shared__ float stat_s[64][2];
    __shared__ float xs[64][68];
    __shared__ float ws[48][64];
    __shared__ float kqkv[48][64];
    __shared__ float pm_s[4][64], ps_s[4][64];
    __shared__ float pool_s[16][17];
    __shared__ float mos[64];
    __shared__ int last_s;

    {
        double s = 0.0, s2 = 0.0;
        for (int bi = wv * 32; bi < wv * 32 + 32; ++bi) {
            s  += dpart2[(bi * 64 + lane) * 2];
            s2 += dpart2[(bi * 64 + lane) * 2 + 1];
        }
        dred[wv][lane][0] = s;
        dred[wv][lane][1] = s2;
    }
    __syncthreads();
    if (tid < 64) {
        double s  = dred[0][tid][0] + dred[1][tid][0] + dred[2][tid][0] + dred[3][tid][0];
        double s2 = dred[0][tid][1] + dred[1][tid][1] + dred[2][tid][1] + dred[3][tid][1];
        double N = (double)(NB * NE);
        double m = s / N;
        double var = s2 / N - m * m;
        stat_s[tid][0] = (float)m;
        stat_s[tid][1] = (float)(1.0 / sqrt(var + 1e-5));
    }
    __syncthreads();
    for (int idx4 = tid; idx4 < 1024; idx4 += 256) {
        int r = idx4 >> 4, c4 = idx4 & 15;
        float4 v = ((const float4*)(x2 + b * 4096))[idx4];
        float m = stat_s[r][0], rs = stat_s[r][1], gg = g[r], bv = bb[r];
        v.x = (v.x - m) * rs * gg + bv; v.x = v.x > 0.f ? v.x : 0.f;
        v.y = (v.y - m) * rs * gg + bv; v.y = v.y > 0.f ? v.y : 0.f;
        v.z = (v.z - m) * rs * gg + bv; v.z = v.z > 0.f ? v.z : 0.f;
        v.w = (v.w - m) * rs * gg + bv; v.w = v.w > 0.f ? v.w : 0.f;
        *(float4*)&xs[r][c4 * 4] = v;
    }
    for (int idx4 = tid; idx4 < 768; idx4 += 256) {
        int rl = idx4 >> 4, c4 = idx4 & 15;
        int rg = ((rl >> 4) << 6) + (h << 4) + (rl & 15);
        *(float4*)&ws[rl][c4 * 4] = ((const float4*)(Win + rg * 64))[c4];
    }
    __syncthreads();

    float acc[12];
    #pragma unroll
    for (int u = 0; u < 12; ++u) {
        int ol = wv + 4 * u;
        acc[u] = bin[((ol >> 4) << 6) + (h << 4) + (ol & 15)];
    }
    #pragma unroll
    for (int d4 = 0; d4 < 16; ++d4) {
        float4 xv = *(const float4*)&xs[lane][d4 * 4];
        #pragma unroll
        for (int u = 0; u < 12; ++u) {
            float4 w = *(const float4*)&ws[wv + 4 * u][d4 * 4];
            acc[u] += xv.x * w.x + xv.y * w.y + xv.z * w.z + xv.w * w.w;
        }
    }
    #pragma unroll
    for (int u = 0; u < 12; ++u) kqkv[wv + 4 * u][lane] = acc[u];
    __syncthreads();

    int j0 = wv * 16;
    float q[16];
    #pragma unroll
    for (int d = 0; d < 16; ++d) q[d] = kqkv[d][lane];
    float sc[16];
    #pragma unroll
    for (int jj = 0; jj < 16; ++jj) sc[jj] = 0.f;
    #pragma unroll
    for (int d = 0; d < 16; ++d) {
        float qd = q[d];
        #pragma unroll
        for (int j4 = 0; j4 < 4; ++j4) {
            float4 kv = *(const float4*)&kqkv[16 + d][j0 + j4 * 4];
            sc[j4 * 4 + 0] += qd * kv.x;
            sc[j4 * 4 + 1] += qd * kv.y;
            sc[j4 * 4 + 2] += qd * kv.z;
            sc[j4 * 4 + 3] += qd * kv.w;
        }
    }
    float pmax = -1e30f;
    #pragma unroll
    for (int jj = 0; jj < 16; ++jj) { sc[jj] *= 0.25f; pmax = fmaxf(pmax, sc[jj]); }
    pm_s[wv][lane] = pmax;
    __syncthreads();
    float mx = fmaxf(fmaxf(pm_s[0][lane], pm_s[1][lane]),
                     fmaxf(pm_s[2][lane], pm_s[3][lane]));
    float psum = 0.f;
    #pragma unroll
    for (int jj = 0; jj < 16; ++jj) { sc[jj] = expf(sc[jj] - mx); psum += sc[jj]; }
    ps_s[wv][lane] = psum;
    float po[16];
    #pragma unroll
    for (int d = 0; d < 16; ++d) {
        float4 v0 = *(const float4*)&kqkv[32 + d][j0 + 0];
        float4 v1 = *(const float4*)&kqkv[32 + d][j0 + 4];
        float4 v2 = *(const float4*)&kqkv[32 + d][j0 + 8];
        float4 v3 = *(const float4*)&kqkv[32 + d][j0 + 12];
        po[d] = sc[0] * v0.x + sc[1] * v0.y + sc[2] * v0.z + sc[3] * v0.w
              + sc[4] * v1.x + sc[5] * v1.y + sc[6] * v1.z + sc[7] * v1.w
              + sc[8] * v2.x + sc[9] * v2.y + sc[10] * v2.z + sc[11] * v2.w
              + sc[12] * v3.x + sc[13] * v3.y + sc[14] * v3.z + sc[15] * v3.w;
    }
    __syncthreads();
    float inv = 1.f / (ps_s[0][lane] + ps_s[1][lane] + ps_s[2][lane] + ps_s[3][lane]);
    if (wv == 0) {
        #pragma unroll
        for (int d = 0; d < 16; ++d) kqkv[d][lane] = po[d];
    }
    __syncthreads();
    if (wv == 1) {
        #pragma unroll
        for (int d = 0; d < 16; ++d) kqkv[d][lane] += po[d];
    }
    __syncthreads();
    if (wv == 2) {
        #pragma unroll
        for (int d = 0; d < 16; ++d) kqkv[d][lane] += po[d];
    }
    __syncthreads();
    if (wv == 3) {
        #pragma unroll
        for (int d = 0; d < 16; ++d)
            kqkv[d][lane] = (kqkv[d][lane] + po[d]) * inv;
    }
    __syncthreads();
    {
        int d = tid & 15, part = tid >> 4;
        float4 v = *(const float4*)&kqkv[d][part * 4];
        pool_s[d][part] = v.x + v.y + v.z + v.w;
    }
    __syncthreads();
    if (tid < 16) {
        float s = 0.f;
        #pragma unroll
        for (int p = 0; p < 16; ++p) s += pool_s[tid][p];
        w_mo[b * 64 + h * 16 + tid] = s * (1.f / 64.f);
    }
    __syncthreads();
    // --- folded projection: 4th-arriving block of this b computes feat[b] ---
    if (tid == 0) {
        __threadfence();             // release w_mo slice
        int old = __hip_atomic_fetch_add(&cnt[b], 1, __ATOMIC_ACQ_REL,
                                         __HIP_MEMORY_SCOPE_AGENT);
        last_s = (old == 3) ? 1 : 0;
    }
    __syncthreads();
    if (last_s) {
        __threadfence();             // acquire all four w_mo slices
        if (tid < 64) mos[tid] = w_mo[b * 64 + tid];
        __syncthreads();
        if (tid < 64) {
            float a = bout[tid];
            const float4* wr = (const float4*)(Wout + tid * 64);
            #pragma unroll
            for (int d4 = 0; d4 < 16; ++d4) {
                float4 w = wr[d4];
                a += mos[d4 * 4 + 0] * w.x + mos[d4 * 4 + 1] * w.y
                   + mos[d4 * 4 + 2] * w.z + mos[d4 * 4 + 3] * w.w;
            }
            feat[b * NE + tid] = a;
        }
    }
}

// ---------------------------------------------------------------------------
extern "C" void kernel_launch(void* const* d_in, const int* in_sizes, int n_in,
                              void* d_out, int out_size, void* d_ws, size_t ws_size,
                              hipStream_t stream) {
    const float* eeg      = (const float*)d_in[0];
    const float* gcn1_w   = (const float*)d_in[1];
    const float* gcn1_b   = (const float*)d_in[2];
    const float* gcn2_w   = (const float*)d_in[3];
    const float* gcn2_b   = (const float*)d_in[4];
    const float* bn1_g    = (const float*)d_in[5];
    const float* bn1_b    = (const float*)d_in[6];
    const float* bn2_g    = (const float*)d_in[7];
    const float* bn2_b    = (const float*)d_in[8];
    const float* attn_in_w  = (const float*)d_in[9];
    const float* attn_in_b  = (const float*)d_in[10];
    const float* attn_out_w = (const float*)d_in[11];
    const float* attn_out_b = (const float*)d_in[12];

    float* out  = (float*)d_out;
    float* feat = out;                          // [B, E]
    float* wpli = out + NB * NE;                // [B, C, C]

    float* ws = (float*)d_ws;
    float*  w_re   = ws;                        // [1M]
    float*  w_im   = ws + 1048576;              // [1M]
    float*  w_x1   = ws + 2097152;              // [1M]
    float*  w_x2   = ws + 3145728;              // [512K]
    float*  w_deg  = ws + 3670016;              // [8K]
    float*  w_mo   = ws + 3678208;              // [8K]
    double* dpart1 = (double*)(ws + 3686400);   // [128*64*2]
    double* dpart2 = (double*)(ws + 3719168);   // [128*64*2]
    int*    sync_i = (int*)(ws + 3751936);      // bar[2] + cnt[128]

    // reset barrier + completion counters (130 ints)
    hipMemsetAsync(sync_i, 0, 520, stream);
    // 1. analytic signal
    analytic_kernel<<<NB * NC, NT, 0, stream>>>(eeg, w_re, w_im);
    // 2. PLI (+deg), writes wpli output
    pli_kernel<<<NB * NC / 4, 256, 0, stream>>>(w_re, w_im, wpli, w_deg);
    // 3. GCN1 + grid-barrier + GCN2 (256 blocks, all resident)
    gcn12<<<NB * 2, 1024, 0, stream>>>(
        wpli, w_deg, eeg, gcn1_w, gcn1_b, gcn2_w, gcn2_b,
        bn1_g, bn1_b, w_x1, w_x2, dpart1, dpart2, sync_i);
    // 4. attention per (b, head) + folded projection
    attn_head<<<NB * NHD, 256, 0, stream>>>(w_x2, dpart2, bn2_g, bn2_b,
                                            attn_in_w, attn_in_b,
                                            attn_out_w, attn_out_b,
                                            w_mo, sync_i + 2, feat);
}

// Round 12
// 128.828 us; speedup vs baseline: 2.2343x; 2.2343x over previous
//
#include <hip/hip_runtime.h>
#include <math.h>

#define NB 128     // batch
#define NC 64      // channels
#define NT 128     // segment length
#define HIDN 128   // hidden
#define NE 64      // attn embed
#define NHD 4      // heads
#define HD 16      // head dim

// ---------------------------------------------------------------------------
// 1. Analytic signal (unchanged; bit-identical math; [b][c][t] layout).
// ---------------------------------------------------------------------------
__global__ void analytic_kernel(const float* __restrict__ eeg,
                                float* __restrict__ re, float* __restrict__ im) {
    int row = blockIdx.x;            // b*NC + c
    int t = threadIdx.x;             // 0..127
    __shared__ float xs[NT];
    __shared__ double cotv[64];
    xs[t] = eeg[row * NT + t];
    if (t < 64) {
        double d = (double)(2 * t + 1);
        double a = 3.14159265358979323846 * d / 128.0;
        cotv[t] = cos(a) / sin(a);
    }
    __syncthreads();
    double ar = 0.0, ai = 0.0;
    #pragma unroll
    for (int m = 0; m < 64; ++m) {
        int d = 2 * m + 1;
        int s = (t - d) & 127;
        double xv = (double)xs[s];
        ar += xv;
        ai += cotv[m] * xv;
    }
    double rr = (double)xs[t] + ar * (1.0 / 64.0);
    double ii = ai * (1.0 / 64.0);
    re[row * NT + t] = (float)rr;
    im[row * NT + t] = (float)ii;
}

// ---------------------------------------------------------------------------
// 2. PLI v3 (unchanged). Bit-identical accumulation.
// ---------------------------------------------------------------------------
__global__ void pli_kernel(const float* __restrict__ re, const float* __restrict__ im,
                           float* __restrict__ wpli, float* __restrict__ deg) {
    int b = blockIdx.x >> 4;
    int i0 = (blockIdx.x & 15) << 2;
    int tid = threadIdx.x;           // 256
    int w = tid >> 6;
    int j = tid & 63;
    __shared__ float4 sre4[64 * 32];
    __shared__ float4 sim4[64 * 32];
    __shared__ int pacc[4][4][64];
    const float* reb = re + b * (NC * NT);
    const float* imb = im + b * (NC * NT);
    for (int idx4 = tid; idx4 < 2048; idx4 += 256) {
        int c = idx4 >> 5, t4 = idx4 & 31;
        int slot = c * 32 + (t4 ^ (c & 31));
        sre4[slot] = ((const float4*)reb)[idx4];
        sim4[slot] = ((const float4*)imb)[idx4];
    }
    __syncthreads();
    int acc0 = 0, acc1 = 0, acc2 = 0, acc3 = 0;
    #pragma unroll
    for (int tt = 0; tt < 8; ++tt) {
        int t4 = w * 8 + tt;
        float4 rj = sre4[j * 32 + (t4 ^ (j & 31))];
        float4 ij = sim4[j * 32 + (t4 ^ (j & 31))];
        #pragma unroll
        for (int di = 0; di < 4; ++di) {
            int i = i0 + di;
            float4 ri = sre4[i * 32 + (t4 ^ (i & 31))];
            float4 ii = sim4[i * 32 + (t4 ^ (i & 31))];
            float c0 = ii.x * rj.x - ri.x * ij.x;
            float c1 = ii.y * rj.y - ri.y * ij.y;
            float c2 = ii.z * rj.z - ri.z * ij.z;
            float c3 = ii.w * rj.w - ri.w * ij.w;
            int d = ((c0 > 0.f) ? 1 : ((c0 < 0.f) ? -1 : 0))
                  + ((c1 > 0.f) ? 1 : ((c1 < 0.f) ? -1 : 0))
                  + ((c2 > 0.f) ? 1 : ((c2 < 0.f) ? -1 : 0))
                  + ((c3 > 0.f) ? 1 : ((c3 < 0.f) ? -1 : 0));
            if (di == 0) acc0 += d;
            else if (di == 1) acc1 += d;
            else if (di == 2) acc2 += d;
            else acc3 += d;
        }
    }
    pacc[w][0][j] = acc0; pacc[w][1][j] = acc1;
    pacc[w][2][j] = acc2; pacc[w][3][j] = acc3;
    __syncthreads();
    int di2 = tid >> 6, j2 = tid & 63;
    int a = pacc[0][di2][j2] + pacc[1][di2][j2] + pacc[2][di2][j2] + pacc[3][di2][j2];
    float p = fabsf((float)a * (1.f / (float)NT));
    int i = i0 + di2;
    if (j2 == i) p = 0.f;
    wpli[b * (NC * NC) + i * NC + j2] = p;
    float s = p;
    #pragma unroll
    for (int off = 32; off > 0; off >>= 1) s += __shfl_down(s, off);
    if (j2 == 0) deg[b * NC + i] = s;
}

// ---------------------------------------------------------------------------
// 3. Fused GCN layer, 2 blocks per batch (unchanged from R9/R10 — verified).
// ---------------------------------------------------------------------------
template <int OUT, bool BN_IN>
__global__ __launch_bounds__(1024, 1) void gcn_fused(
        const float* __restrict__ adj, const float* __restrict__ deg,
        const float* __restrict__ x, const double* __restrict__ dpart_in,
        const float* __restrict__ g, const float* __restrict__ bb,
        const float* __restrict__ W, const float* __restrict__ bias,
        float* __restrict__ xout, double* __restrict__ dpart_out) {
    int b = blockIdx.x >> 1;
    int half = blockIdx.x & 1;
    int tid = threadIdx.x;           // 1024
    __shared__ float dn_s[64];
    __shared__ float stat_s[64][2];
    __shared__ float arow[32][68];
    __shared__ float xs[64][128];
    __shared__ float sup[32][132];
    __shared__ float WsT[128][(OUT == 128) ? 132 : 68];  // [k][o]
    __shared__ double dred[16][64][2];

    if (BN_IN) {
        int c = tid & 63, chunk = tid >> 6;
        double s = 0.0, s2 = 0.0;
        for (int bi = chunk * 8; bi < chunk * 8 + 8; ++bi) {
            s  += dpart_in[(bi * 64 + c) * 2];
            s2 += dpart_in[(bi * 64 + c) * 2 + 1];
        }
        dred[chunk][c][0] = s;
        dred[chunk][c][1] = s2;
    }
    if (tid < 64)
        dn_s[tid] = (float)(1.0 / sqrt((double)deg[b * 64 + tid] + 1e-8));
    __syncthreads();
    if (BN_IN && tid < 64) {
        double s = 0.0, s2 = 0.0;
        for (int ch = 0; ch < 16; ++ch) {
            s  += dred[ch][tid][0];
            s2 += dred[ch][tid][1];
        }
        double N = (double)(NB * HIDN);
        double m = s / N;
        double var = s2 / N - m * m;
        stat_s[tid][0] = (float)m;
        stat_s[tid][1] = (float)(1.0 / sqrt(var + 1e-5));
    }
    __syncthreads();
    if (tid < 512) {
        int il = tid >> 4, j4 = tid & 15;
        int i = half * 32 + il;
        float4 v = *(const float4*)&adj[b * 4096 + i * 64 + j4 * 4];
        float di = dn_s[i];
        v.x *= di * dn_s[j4 * 4 + 0];
        v.y *= di * dn_s[j4 * 4 + 1];
        v.z *= di * dn_s[j4 * 4 + 2];
        v.w *= di * dn_s[j4 * 4 + 3];
        *(float4*)&arow[il][j4 * 4] = v;
    }
    #pragma unroll
    for (int p = 0; p < 2; ++p) {
        int idx4 = tid + p * 1024;
        int r = idx4 >> 5, c4 = idx4 & 31;
        float4 v = ((const float4*)(x + b * 8192))[idx4];
        if (BN_IN) {
            float m = stat_s[r][0], rs = stat_s[r][1], gg = g[r], bv = bb[r];
            v.x = (v.x - m) * rs * gg + bv; v.x = v.x > 0.f ? v.x : 0.f;
            v.y = (v.y - m) * rs * gg + bv; v.y = v.y > 0.f ? v.y : 0.f;
            v.z = (v.z - m) * rs * gg + bv; v.z = v.z > 0.f ? v.z : 0.f;
            v.w = (v.w - m) * rs * gg + bv; v.w = v.w > 0.f ? v.w : 0.f;
        }
        *(float4*)&xs[r][c4 * 4] = v;
    }
    #pragma unroll
    for (int p = 0; p < OUT / 32; ++p) {
        int idx4 = tid + p * 1024;
        int o = idx4 & (OUT - 1);
        int k4 = idx4 / OUT;
        float4 w = *(const float4*)&W[o * 128 + k4 * 4];
        WsT[k4 * 4 + 0][o] = w.x;
        WsT[k4 * 4 + 1][o] = w.y;
        WsT[k4 * 4 + 2][o] = w.z;
        WsT[k4 * 4 + 3][o] = w.w;
    }
    __syncthreads();

    int il = tid >> 5;
    int i = half * 32 + il;
    {
        int f0 = (tid & 31) * 4;
        float a0 = 0.f, a1 = 0.f, a2 = 0.f, a3 = 0.f;
        #pragma unroll 8
        for (int j = 0; j < 64; ++j) {
            float a = arow[il][j];
            float4 xv = *(const float4*)&xs[j][f0];
            a0 += a * xv.x; a1 += a * xv.y; a2 += a * xv.z; a3 += a * xv.w;
        }
        *(float4*)&sup[il][f0] = make_float4(a0, a1, a2, a3);
    }
    __syncthreads();

    double ds = 0.0, ds2 = 0.0;
    if (OUT == 128) {
        int o0 = (tid & 31) * 4;
        float c[4] = {};
        #pragma unroll 8
        for (int k = 0; k < 128; ++k) {
            float s = sup[il][k];
            float4 w0 = *(const float4*)&WsT[k][o0];
            c[0] += s * w0.x; c[1] += s * w0.y; c[2] += s * w0.z; c[3] += s * w0.w;
        }
        float4 r0 = make_float4(c[0] + bias[o0], c[1] + bias[o0 + 1],
                                c[2] + bias[o0 + 2], c[3] + bias[o0 + 3]);
        *(float4*)&xout[b * 64 * 128 + i * 128 + o0] = r0;
        ds  = (double)r0.x + (double)r0.y + (double)r0.z + (double)r0.w;
        ds2 = (double)r0.x * r0.x + (double)r0.y * r0.y
            + (double)r0.z * r0.z + (double)r0.w * r0.w;
    } else {
        int o0 = (tid & 31) * 2;
        float c0 = 0.f, c1 = 0.f;
        #pragma unroll 8
        for (int k = 0; k < 128; ++k) {
            float s = sup[il][k];
            c0 += s * WsT[k][o0];
            c1 += s * WsT[k][o0 + 1];
        }
        c0 += bias[o0];
        c1 += bias[o0 + 1];
        *(float2*)&xout[b * 64 * 64 + i * 64 + o0] = make_float2(c0, c1);
        ds  = (double)c0 + (double)c1;
        ds2 = (double)c0 * c0 + (double)c1 * c1;
    }
    #pragma unroll
    for (int off = 16; off > 0; off >>= 1) {
        ds  += __shfl_down(ds, off, 32);
        ds2 += __shfl_down(ds2, off, 32);
    }
    if ((tid & 31) == 0) {
        dpart_out[(b * 64 + i) * 2]     = ds;
        dpart_out[(b * 64 + i) * 2 + 1] = ds2;
    }
}

// ---------------------------------------------------------------------------
// 4. Attention per (b, head) + folded out-projection (R10 math + R11 fold).
//    4th-arriving block of each b (order-independent result) computes feat[b].
// ---------------------------------------------------------------------------
__global__ __launch_bounds__(256) void attn_head(
        const float* __restrict__ x2, const double* __restrict__ dpart2,
        const float* __restrict__ g, const float* __restrict__ bb,
        const float* __restrict__ Win, const float* __restrict__ bin,
        const float* __restrict__ Wout, const float* __restrict__ bout,
        float* __restrict__ w_mo, int* __restrict__ cnt,
        float* __restrict__ feat) {
    int b = blockIdx.x >> 2, h = blockIdx.x & 3;
    int tid = threadIdx.x;
    int lane = tid & 63, wv = tid >> 6;
    __shared__ double dred[4][64][2];
    __shared__ float stat_s[64][2];
    __shared__ float xs[64][68];
    __shared__ float ws[48][64];
    __shared__ float kqkv[48][64];
    __shared__ float pm_s[4][64], ps_s[4][64];
    __shared__ float pool_s[16][17];
    __shared__ float mos[64];
    __shared__ int last_s;

    {
        double s = 0.0, s2 = 0.0;
        for (int bi = wv * 32; bi < wv * 32 + 32; ++bi) {
            s  += dpart2[(bi * 64 + lane) * 2];
            s2 += dpart2[(bi * 64 + lane) * 2 + 1];
        }
        dred[wv][lane][0] = s;
        dred[wv][lane][1] = s2;
    }
    __syncthreads();
    if (tid < 64) {
        double s  = dred[0][tid][0] + dred[1][tid][0] + dred[2][tid][0] + dred[3][tid][0];
        double s2 = dred[0][tid][1] + dred[1][tid][1] + dred[2][tid][1] + dred[3][tid][1];
        double N = (double)(NB * NE);
        double m = s / N;
        double var = s2 / N - m * m;
        stat_s[tid][0] = (float)m;
        stat_s[tid][1] = (float)(1.0 / sqrt(var + 1e-5));
    }
    __syncthreads();
    for (int idx4 = tid; idx4 < 1024; idx4 += 256) {
        int r = idx4 >> 4, c4 = idx4 & 15;
        float4 v = ((const float4*)(x2 + b * 4096))[idx4];
        float m = stat_s[r][0], rs = stat_s[r][1], gg = g[r], bv = bb[r];
        v.x = (v.x - m) * rs * gg + bv; v.x = v.x > 0.f ? v.x : 0.f;
        v.y = (v.y - m) * rs * gg + bv; v.y = v.y > 0.f ? v.y : 0.f;
        v.z = (v.z - m) * rs * gg + bv; v.z = v.z > 0.f ? v.z : 0.f;
        v.w = (v.w - m) * rs * gg + bv; v.w = v.w > 0.f ? v.w : 0.f;
        *(float4*)&xs[r][c4 * 4] = v;
    }
    for (int idx4 = tid; idx4 < 768; idx4 += 256) {
        int rl = idx4 >> 4, c4 = idx4 & 15;
        int rg = ((rl >> 4) << 6) + (h << 4) + (rl & 15);
        *(float4*)&ws[rl][c4 * 4] = ((const float4*)(Win + rg * 64))[c4];
    }
    __syncthreads();

    float acc[12];
    #pragma unroll
    for (int u = 0; u < 12; ++u) {
        int ol = wv + 4 * u;
        acc[u] = bin[((ol >> 4) << 6) + (h << 4) + (ol & 15)];
    }
    #pragma unroll
    for (int d4 = 0; d4 < 16; ++d4) {
        float4 xv = *(const float4*)&xs[lane][d4 * 4];
        #pragma unroll
        for (int u = 0; u < 12; ++u) {
            float4 w = *(const float4*)&ws[wv + 4 * u][d4 * 4];
            acc[u] += xv.x * w.x + xv.y * w.y + xv.z * w.z + xv.w * w.w;
        }
    }
    #pragma unroll
    for (int u = 0; u < 12; ++u) kqkv[wv + 4 * u][lane] = acc[u];
    __syncthreads();

    int j0 = wv * 16;
    float q[16];
    #pragma unroll
    for (int d = 0; d < 16; ++d) q[d] = kqkv[d][lane];
    float sc[16];
    #pragma unroll
    for (int jj = 0; jj < 16; ++jj) sc[jj] = 0.f;
    #pragma unroll
    for (int d = 0; d < 16; ++d) {
        float qd = q[d];
        #pragma unroll
        for (int j4 = 0; j4 < 4; ++j4) {
            float4 kv = *(const float4*)&kqkv[16 + d][j0 + j4 * 4];
            sc[j4 * 4 + 0] += qd * kv.x;
            sc[j4 * 4 + 1] += qd * kv.y;
            sc[j4 * 4 + 2] += qd * kv.z;
            sc[j4 * 4 + 3] += qd * kv.w;
        }
    }
    float pmax = -1e30f;
    #pragma unroll
    for (int jj = 0; jj < 16; ++jj) { sc[jj] *= 0.25f; pmax = fmaxf(pmax, sc[jj]); }
    pm_s[wv][lane] = pmax;
    __syncthreads();
    float mx = fmaxf(fmaxf(pm_s[0][lane], pm_s[1][lane]),
                     fmaxf(pm_s[2][lane], pm_s[3][lane]));
    float psum = 0.f;
    #pragma unroll
    for (int jj = 0; jj < 16; ++jj) { sc[jj] = expf(sc[jj] - mx); psum += sc[jj]; }
    ps_s[wv][lane] = psum;
    float po[16];
    #pragma unroll
    for (int d = 0; d < 16; ++d) {
        float4 v0 = *(const float4*)&kqkv[32 + d][j0 + 0];
        float4 v1 = *(const float4*)&kqkv[32 + d][j0 + 4];
        float4 v2 = *(const float4*)&kqkv[32 + d][j0 + 8];
        float4 v3 = *(const float4*)&kqkv[32 + d][j0 + 12];
        po[d] = sc[0] * v0.x + sc[1] * v0.y + sc[2] * v0.z + sc[3] * v0.w
              + sc[4] * v1.x + sc[5] * v1.y + sc[6] * v1.z + sc[7] * v1.w
              + sc[8] * v2.x + sc[9] * v2.y + sc[10] * v2.z + sc[11] * v2.w
              + sc[12] * v3.x + sc[13] * v3.y + sc[14] * v3.z + sc[15] * v3.w;
    }
    __syncthreads();
    float inv = 1.f / (ps_s[0][lane] + ps_s[1][lane] + ps_s[2][lane] + ps_s[3][lane]);
    if (wv == 0) {
        #pragma unroll
        for (int d = 0; d < 16; ++d) kqkv[d][lane] = po[d];
    }
    __syncthreads();
    if (wv == 1) {
        #pragma unroll
        for (int d = 0; d < 16; ++d) kqkv[d][lane] += po[d];
    }
    __syncthreads();
    if (wv == 2) {
        #pragma unroll
        for (int d = 0; d < 16; ++d) kqkv[d][lane] += po[d];
    }
    __syncthreads();
    if (wv == 3) {
        #pragma unroll
        for (int d = 0; d < 16; ++d)
            kqkv[d][lane] = (kqkv[d][lane] + po[d]) * inv;
    }
    __syncthreads();
    {
        int d = tid & 15, part = tid >> 4;
        float4 v = *(const float4*)&kqkv[d][part * 4];
        pool_s[d][part] = v.x + v.y + v.z + v.w;
    }
    __syncthreads();
    if (tid < 16) {
        float s = 0.f;
        #pragma unroll
        for (int p = 0; p < 16; ++p) s += pool_s[tid][p];
        w_mo[b * 64 + h * 16 + tid] = s * (1.f / 64.f);
    }
    __syncthreads();
    // folded projection: 4th-arriving block of this b computes feat[b]
    if (tid == 0) {
        __threadfence();
        int old = __hip_atomic_fetch_add(&cnt[b], 1, __ATOMIC_ACQ_REL,
                                         __HIP_MEMORY_SCOPE_AGENT);
        last_s = (old == 3) ? 1 : 0;
    }
    __syncthreads();
    if (last_s) {
        __threadfence();
        if (tid < 64) mos[tid] = w_mo[b * 64 + tid];
        __syncthreads();
        if (tid < 64) {
            float a = bout[tid];
            const float4* wr = (const float4*)(Wout + tid * 64);
            #pragma unroll
            for (int d4 = 0; d4 < 16; ++d4) {
                float4 w = wr[d4];
                a += mos[d4 * 4 + 0] * w.x + mos[d4 * 4 + 1] * w.y
                   + mos[d4 * 4 + 2] * w.z + mos[d4 * 4 + 3] * w.w;
            }
            feat[b * NE + tid] = a;
        }
    }
}

// ---------------------------------------------------------------------------
extern "C" void kernel_launch(void* const* d_in, const int* in_sizes, int n_in,
                              void* d_out, int out_size, void* d_ws, size_t ws_size,
                              hipStream_t stream) {
    const float* eeg      = (const float*)d_in[0];
    const float* gcn1_w   = (const float*)d_in[1];
    const float* gcn1_b   = (const float*)d_in[2];
    const float* gcn2_w   = (const float*)d_in[3];
    const float* gcn2_b   = (const float*)d_in[4];
    const float* bn1_g    = (const float*)d_in[5];
    const float* bn1_b    = (const float*)d_in[6];
    const float* bn2_g    = (const float*)d_in[7];
    const float* bn2_b    = (const float*)d_in[8];
    const float* attn_in_w  = (const float*)d_in[9];
    const float* attn_in_b  = (const float*)d_in[10];
    const float* attn_out_w = (const float*)d_in[11];
    const float* attn_out_b = (const float*)d_in[12];

    float* out  = (float*)d_out;
    float* feat = out;                          // [B, E]
    float* wpli = out + NB * NE;                // [B, C, C]

    float* ws = (float*)d_ws;
    float*  w_re   = ws;                        // [1M]
    float*  w_im   = ws + 1048576;              // [1M]
    float*  w_x1   = ws + 2097152;              // [1M]
    float*  w_x2   = ws + 3145728;              // [512K]
    float*  w_deg  = ws + 3670016;              // [8K]
    float*  w_mo   = ws + 3678208;              // [8K]
    double* dpart1 = (double*)(ws + 3686400);   // [128*64*2]
    double* dpart2 = (double*)(ws + 3719168);   // [128*64*2]
    int*    cnt    = (int*)(ws + 3751936);      // [128]

    // reset per-batch completion counters
    hipMemsetAsync(cnt, 0, 512, stream);
    // 1. analytic signal
    analytic_kernel<<<NB * NC, NT, 0, stream>>>(eeg, w_re, w_im);
    // 2. PLI (+deg), writes wpli output
    pli_kernel<<<NB * NC / 4, 256, 0, stream>>>(w_re, w_im, wpli, w_deg);
    // 3. GCN1 fused, 2 blocks/batch
    gcn_fused<HIDN, false><<<NB * 2, 1024, 0, stream>>>(
        wpli, w_deg, eeg, nullptr, nullptr, nullptr,
        gcn1_w, gcn1_b, w_x1, dpart1);
    // 4. GCN2 fused, 2 blocks/batch
    gcn_fused<NE, true><<<NB * 2, 1024, 0, stream>>>(
        wpli, w_deg, w_x1, dpart1, bn1_g, bn1_b,
        gcn2_w, gcn2_b, w_x2, dpart2);
    // 5. attention per (b, head) + folded projection
    attn_head<<<NB * NHD, 256, 0, stream>>>(w_x2, dpart2, bn2_g, bn2_b,
                                            attn_in_w, attn_in_b,
                                            attn_out_w, attn_out_b,
                                            w_mo, cnt, feat);
}

// Round 13
// 98.879 us; speedup vs baseline: 2.9110x; 1.3029x over previous
//
#include <hip/hip_runtime.h>
#include <math.h>

#define NB 128     // batch
#define NC 64      // channels
#define NT 128     // segment length
#define HIDN 128   // hidden
#define NE 64      // attn embed
#define NHD 4      // heads
#define HD 16      // head dim

// ---------------------------------------------------------------------------
// 1. Analytic signal (bit-identical math; [b][c][t] layout).
// ---------------------------------------------------------------------------
__global__ void analytic_kernel(const float* __restrict__ eeg,
                                float* __restrict__ re, float* __restrict__ im) {
    int row = blockIdx.x;            // b*NC + c
    int t = threadIdx.x;             // 0..127
    __shared__ float xs[NT];
    __shared__ double cotv[64];
    xs[t] = eeg[row * NT + t];
    if (t < 64) {
        double d = (double)(2 * t + 1);
        double a = 3.14159265358979323846 * d / 128.0;
        cotv[t] = cos(a) / sin(a);
    }
    __syncthreads();
    double ar = 0.0, ai = 0.0;
    #pragma unroll
    for (int m = 0; m < 64; ++m) {
        int d = 2 * m + 1;
        int s = (t - d) & 127;
        double xv = (double)xs[s];
        ar += xv;
        ai += cotv[m] * xv;
    }
    double rr = (double)xs[t] + ar * (1.0 / 64.0);
    double ii = ai * (1.0 / 64.0);
    re[row * NT + t] = (float)rr;
    im[row * NT + t] = (float)ii;
}

// ---------------------------------------------------------------------------
// 2. PLI v3 (bit-identical accumulation).
// ---------------------------------------------------------------------------
__global__ void pli_kernel(const float* __restrict__ re, const float* __restrict__ im,
                           float* __restrict__ wpli, float* __restrict__ deg) {
    int b = blockIdx.x >> 4;
    int i0 = (blockIdx.x & 15) << 2;
    int tid = threadIdx.x;           // 256
    int w = tid >> 6;
    int j = tid & 63;
    __shared__ float4 sre4[64 * 32];
    __shared__ float4 sim4[64 * 32];
    __shared__ int pacc[4][4][64];
    const float* reb = re + b * (NC * NT);
    const float* imb = im + b * (NC * NT);
    for (int idx4 = tid; idx4 < 2048; idx4 += 256) {
        int c = idx4 >> 5, t4 = idx4 & 31;
        int slot = c * 32 + (t4 ^ (c & 31));
        sre4[slot] = ((const float4*)reb)[idx4];
        sim4[slot] = ((const float4*)imb)[idx4];
    }
    __syncthreads();
    int acc0 = 0, acc1 = 0, acc2 = 0, acc3 = 0;
    #pragma unroll
    for (int tt = 0; tt < 8; ++tt) {
        int t4 = w * 8 + tt;
        float4 rj = sre4[j * 32 + (t4 ^ (j & 31))];
        float4 ij = sim4[j * 32 + (t4 ^ (j & 31))];
        #pragma unroll
        for (int di = 0; di < 4; ++di) {
            int i = i0 + di;
            float4 ri = sre4[i * 32 + (t4 ^ (i & 31))];
            float4 ii = sim4[i * 32 + (t4 ^ (i & 31))];
            float c0 = ii.x * rj.x - ri.x * ij.x;
            float c1 = ii.y * rj.y - ri.y * ij.y;
            float c2 = ii.z * rj.z - ri.z * ij.z;
            float c3 = ii.w * rj.w - ri.w * ij.w;
            int d = ((c0 > 0.f) ? 1 : ((c0 < 0.f) ? -1 : 0))
                  + ((c1 > 0.f) ? 1 : ((c1 < 0.f) ? -1 : 0))
                  + ((c2 > 0.f) ? 1 : ((c2 < 0.f) ? -1 : 0))
                  + ((c3 > 0.f) ? 1 : ((c3 < 0.f) ? -1 : 0));
            if (di == 0) acc0 += d;
            else if (di == 1) acc1 += d;
            else if (di == 2) acc2 += d;
            else acc3 += d;
        }
    }
    pacc[w][0][j] = acc0; pacc[w][1][j] = acc1;
    pacc[w][2][j] = acc2; pacc[w][3][j] = acc3;
    __syncthreads();
    int di2 = tid >> 6, j2 = tid & 63;
    int a = pacc[0][di2][j2] + pacc[1][di2][j2] + pacc[2][di2][j2] + pacc[3][di2][j2];
    float p = fabsf((float)a * (1.f / (float)NT));
    int i = i0 + di2;
    if (j2 == i) p = 0.f;
    wpli[b * (NC * NC) + i * NC + j2] = p;
    float s = p;
    #pragma unroll
    for (int off = 32; off > 0; off >>= 1) s += __shfl_down(s, off);
    if (j2 == 0) deg[b * NC + i] = s;
}

// ---------------------------------------------------------------------------
// 3. Fused GCN layer, 2 blocks per batch (verified R9/R10).
// ---------------------------------------------------------------------------
template <int OUT, bool BN_IN>
__global__ __launch_bounds__(1024, 1) void gcn_fused(
        const float* __restrict__ adj, const float* __restrict__ deg,
        const float* __restrict__ x, const double* __restrict__ dpart_in,
        const float* __restrict__ g, const float* __restrict__ bb,
        const float* __restrict__ W, const float* __restrict__ bias,
        float* __restrict__ xout, double* __restrict__ dpart_out) {
    int b = blockIdx.x >> 1;
    int half = blockIdx.x & 1;
    int tid = threadIdx.x;           // 1024
    __shared__ float dn_s[64];
    __shared__ float stat_s[64][2];
    __shared__ float arow[32][68];
    __shared__ float xs[64][128];
    __shared__ float sup[32][132];
    __shared__ float WsT[128][(OUT == 128) ? 132 : 68];  // [k][o]
    __shared__ double dred[16][64][2];

    if (BN_IN) {
        int c = tid & 63, chunk = tid >> 6;
        double s = 0.0, s2 = 0.0;
        for (int bi = chunk * 8; bi < chunk * 8 + 8; ++bi) {
            s  += dpart_in[(bi * 64 + c) * 2];
            s2 += dpart_in[(bi * 64 + c) * 2 + 1];
        }
        dred[chunk][c][0] = s;
        dred[chunk][c][1] = s2;
    }
    if (tid < 64)
        dn_s[tid] = (float)(1.0 / sqrt((double)deg[b * 64 + tid] + 1e-8));
    __syncthreads();
    if (BN_IN && tid < 64) {
        double s = 0.0, s2 = 0.0;
        for (int ch = 0; ch < 16; ++ch) {
            s  += dred[ch][tid][0];
            s2 += dred[ch][tid][1];
        }
        double N = (double)(NB * HIDN);
        double m = s / N;
        double var = s2 / N - m * m;
        stat_s[tid][0] = (float)m;
        stat_s[tid][1] = (float)(1.0 / sqrt(var + 1e-5));
    }
    __syncthreads();
    if (tid < 512) {
        int il = tid >> 4, j4 = tid & 15;
        int i = half * 32 + il;
        float4 v = *(const float4*)&adj[b * 4096 + i * 64 + j4 * 4];
        float di = dn_s[i];
        v.x *= di * dn_s[j4 * 4 + 0];
        v.y *= di * dn_s[j4 * 4 + 1];
        v.z *= di * dn_s[j4 * 4 + 2];
        v.w *= di * dn_s[j4 * 4 + 3];
        *(float4*)&arow[il][j4 * 4] = v;
    }
    #pragma unroll
    for (int p = 0; p < 2; ++p) {
        int idx4 = tid + p * 1024;
        int r = idx4 >> 5, c4 = idx4 & 31;
        float4 v = ((const float4*)(x + b * 8192))[idx4];
        if (BN_IN) {
            float m = stat_s[r][0], rs = stat_s[r][1], gg = g[r], bv = bb[r];
            v.x = (v.x - m) * rs * gg + bv; v.x = v.x > 0.f ? v.x : 0.f;
            v.y = (v.y - m) * rs * gg + bv; v.y = v.y > 0.f ? v.y : 0.f;
            v.z = (v.z - m) * rs * gg + bv; v.z = v.z > 0.f ? v.z : 0.f;
            v.w = (v.w - m) * rs * gg + bv; v.w = v.w > 0.f ? v.w : 0.f;
        }
        *(float4*)&xs[r][c4 * 4] = v;
    }
    #pragma unroll
    for (int p = 0; p < OUT / 32; ++p) {
        int idx4 = tid + p * 1024;
        int o = idx4 & (OUT - 1);
        int k4 = idx4 / OUT;
        float4 w = *(const float4*)&W[o * 128 + k4 * 4];
        WsT[k4 * 4 + 0][o] = w.x;
        WsT[k4 * 4 + 1][o] = w.y;
        WsT[k4 * 4 + 2][o] = w.z;
        WsT[k4 * 4 + 3][o] = w.w;
    }
    __syncthreads();

    int il = tid >> 5;
    int i = half * 32 + il;
    {
        int f0 = (tid & 31) * 4;
        float a0 = 0.f, a1 = 0.f, a2 = 0.f, a3 = 0.f;
        #pragma unroll 8
        for (int j = 0; j < 64; ++j) {
            float a = arow[il][j];
            float4 xv = *(const float4*)&xs[j][f0];
            a0 += a * xv.x; a1 += a * xv.y; a2 += a * xv.z; a3 += a * xv.w;
        }
        *(float4*)&sup[il][f0] = make_float4(a0, a1, a2, a3);
    }
    __syncthreads();

    double ds = 0.0, ds2 = 0.0;
    if (OUT == 128) {
        int o0 = (tid & 31) * 4;
        float c[4] = {};
        #pragma unroll 8
        for (int k = 0; k < 128; ++k) {
            float s = sup[il][k];
            float4 w0 = *(const float4*)&WsT[k][o0];
            c[0] += s * w0.x; c[1] += s * w0.y; c[2] += s * w0.z; c[3] += s * w0.w;
        }
        float4 r0 = make_float4(c[0] + bias[o0], c[1] + bias[o0 + 1],
                                c[2] + bias[o0 + 2], c[3] + bias[o0 + 3]);
        *(float4*)&xout[b * 64 * 128 + i * 128 + o0] = r0;
        ds  = (double)r0.x + (double)r0.y + (double)r0.z + (double)r0.w;
        ds2 = (double)r0.x * r0.x + (double)r0.y * r0.y
            + (double)r0.z * r0.z + (double)r0.w * r0.w;
    } else {
        int o0 = (tid & 31) * 2;
        float c0 = 0.f, c1 = 0.f;
        #pragma unroll 8
        for (int k = 0; k < 128; ++k) {
            float s = sup[il][k];
            c0 += s * WsT[k][o0];
            c1 += s * WsT[k][o0 + 1];
        }
        c0 += bias[o0];
        c1 += bias[o0 + 1];
        *(float2*)&xout[b * 64 * 64 + i * 64 + o0] = make_float2(c0, c1);
        ds  = (double)c0 + (double)c1;
        ds2 = (double)c0 * c0 + (double)c1 * c1;
    }
    #pragma unroll
    for (int off = 16; off > 0; off >>= 1) {
        ds  += __shfl_down(ds, off, 32);
        ds2 += __shfl_down(ds2, off, 32);
    }
    if ((tid & 31) == 0) {
        dpart_out[(b * 64 + i) * 2]     = ds;
        dpart_out[(b * 64 + i) * 2 + 1] = ds2;
    }
}

// ---------------------------------------------------------------------------
// 4. Attention per (b, head), 256 threads (verified R10; no atomics/fences).
// ---------------------------------------------------------------------------
__global__ __launch_bounds__(256) void attn_head(
        const float* __restrict__ x2, const double* __restrict__ dpart2,
        const float* __restrict__ g, const float* __restrict__ bb,
        const float* __restrict__ Win, const float* __restrict__ bin,
        float* __restrict__ w_mo) {
    int b = blockIdx.x >> 2, h = blockIdx.x & 3;
    int tid = threadIdx.x;
    int lane = tid & 63, wv = tid >> 6;
    __shared__ double dred[4][64][2];
    __shared__ float stat_s[64][2];
    __shared__ float xs[64][68];
    __shared__ float ws[48][64];
    __shared__ float kqkv[48][64];
    __shared__ float pm_s[4][64], ps_s[4][64];
    __shared__ float pool_s[16][17];

    {
        double s = 0.0, s2 = 0.0;
        for (int bi = wv * 32; bi < wv * 32 + 32; ++bi) {
            s  += dpart2[(bi * 64 + lane) * 2];
            s2 += dpart2[(bi * 64 + lane) * 2 + 1];
        }
        dred[wv][lane][0] = s;
        dred[wv][lane][1] = s2;
    }
    __syncthreads();
    if (tid < 64) {
        double s  = dred[0][tid][0] + dred[1][tid][0] + dred[2][tid][0] + dred[3][tid][0];
        double s2 = dred[0][tid][1] + dred[1][tid][1] + dred[2][tid][1] + dred[3][tid][1];
        double N = (double)(NB * NE);
        double m = s / N;
        double var = s2 / N - m * m;
        stat_s[tid][0] = (float)m;
        stat_s[tid][1] = (float)(1.0 / sqrt(var + 1e-5));
    }
    __syncthreads();
    for (int idx4 = tid; idx4 < 1024; idx4 += 256) {
        int r = idx4 >> 4, c4 = idx4 & 15;
        float4 v = ((const float4*)(x2 + b * 4096))[idx4];
        float m = stat_s[r][0], rs = stat_s[r][1], gg = g[r], bv = bb[r];
        v.x = (v.x - m) * rs * gg + bv; v.x = v.x > 0.f ? v.x : 0.f;
        v.y = (v.y - m) * rs * gg + bv; v.y = v.y > 0.f ? v.y : 0.f;
        v.z = (v.z - m) * rs * gg + bv; v.z = v.z > 0.f ? v.z : 0.f;
        v.w = (v.w - m) * rs * gg + bv; v.w = v.w > 0.f ? v.w : 0.f;
        *(float4*)&xs[r][c4 * 4] = v;
    }
    for (int idx4 = tid; idx4 < 768; idx4 += 256) {
        int rl = idx4 >> 4, c4 = idx4 & 15;
        int rg = ((rl >> 4) << 6) + (h << 4) + (rl & 15);
        *(float4*)&ws[rl][c4 * 4] = ((const float4*)(Win + rg * 64))[c4];
    }
    __syncthreads();

    float acc[12];
    #pragma unroll
    for (int u = 0; u < 12; ++u) {
        int ol = wv + 4 * u;
        acc[u] = bin[((ol >> 4) << 6) + (h << 4) + (ol & 15)];
    }
    #pragma unroll
    for (int d4 = 0; d4 < 16; ++d4) {
        float4 xv = *(const float4*)&xs[lane][d4 * 4];
        #pragma unroll
        for (int u = 0; u < 12; ++u) {
            float4 w = *(const float4*)&ws[wv + 4 * u][d4 * 4];
            acc[u] += xv.x * w.x + xv.y * w.y + xv.z * w.z + xv.w * w.w;
        }
    }
    #pragma unroll
    for (int u = 0; u < 12; ++u) kqkv[wv + 4 * u][lane] = acc[u];
    __syncthreads();

    int j0 = wv * 16;
    float q[16];
    #pragma unroll
    for (int d = 0; d < 16; ++d) q[d] = kqkv[d][lane];
    float sc[16];
    #pragma unroll
    for (int jj = 0; jj < 16; ++jj) sc[jj] = 0.f;
    #pragma unroll
    for (int d = 0; d < 16; ++d) {
        float qd = q[d];
        #pragma unroll
        for (int j4 = 0; j4 < 4; ++j4) {
            float4 kv = *(const float4*)&kqkv[16 + d][j0 + j4 * 4];
            sc[j4 * 4 + 0] += qd * kv.x;
            sc[j4 * 4 + 1] += qd * kv.y;
            sc[j4 * 4 + 2] += qd * kv.z;
            sc[j4 * 4 + 3] += qd * kv.w;
        }
    }
    float pmax = -1e30f;
    #pragma unroll
    for (int jj = 0; jj < 16; ++jj) { sc[jj] *= 0.25f; pmax = fmaxf(pmax, sc[jj]); }
    pm_s[wv][lane] = pmax;
    __syncthreads();
    float mx = fmaxf(fmaxf(pm_s[0][lane], pm_s[1][lane]),
                     fmaxf(pm_s[2][lane], pm_s[3][lane]));
    float psum = 0.f;
    #pragma unroll
    for (int jj = 0; jj < 16; ++jj) { sc[jj] = expf(sc[jj] - mx); psum += sc[jj]; }
    ps_s[wv][lane] = psum;
    float po[16];
    #pragma unroll
    for (int d = 0; d < 16; ++d) {
        float4 v0 = *(const float4*)&kqkv[32 + d][j0 + 0];
        float4 v1 = *(const float4*)&kqkv[32 + d][j0 + 4];
        float4 v2 = *(const float4*)&kqkv[32 + d][j0 + 8];
        float4 v3 = *(const float4*)&kqkv[32 + d][j0 + 12];
        po[d] = sc[0] * v0.x + sc[1] * v0.y + sc[2] * v0.z + sc[3] * v0.w
              + sc[4] * v1.x + sc[5] * v1.y + sc[6] * v1.z + sc[7] * v1.w
              + sc[8] * v2.x + sc[9] * v2.y + sc[10] * v2.z + sc[11] * v2.w
              + sc[12] * v3.x + sc[13] * v3.y + sc[14] * v3.z + sc[15] * v3.w;
    }
    __syncthreads();
    float inv = 1.f / (ps_s[0][lane] + ps_s[1][lane] + ps_s[2][lane] + ps_s[3][lane]);
    if (wv == 0) {
        #pragma unroll
        for (int d = 0; d < 16; ++d) kqkv[d][lane] = po[d];
    }
    __syncthreads();
    if (wv == 1) {
        #pragma unroll
        for (int d = 0; d < 16; ++d) kqkv[d][lane] += po[d];
    }
    __syncthreads();
    if (wv == 2) {
        #pragma unroll
        for (int d = 0; d < 16; ++d) kqkv[d][lane] += po[d];
    }
    __syncthreads();
    if (wv == 3) {
        #pragma unroll
        for (int d = 0; d < 16; ++d)
            kqkv[d][lane] = (kqkv[d][lane] + po[d]) * inv;
    }
    __syncthreads();
    {
        int d = tid & 15, part = tid >> 4;
        float4 v = *(const float4*)&kqkv[d][part * 4];
        pool_s[d][part] = v.x + v.y + v.z + v.w;
    }
    __syncthreads();
    if (tid < 16) {
        float s = 0.f;
        #pragma unroll
        for (int p = 0; p < 16; ++p) s += pool_s[tid][p];
        w_mo[b * 64 + h * 16 + tid] = s * (1.f / 64.f);
    }
}

// ---------------------------------------------------------------------------
// 5. Output projection: feat[b][e] = bout[e] + sum_d Wout[e][d] * mo[b][d]
// ---------------------------------------------------------------------------
__global__ void proj_kernel(const float* __restrict__ w_mo,
                            const float* __restrict__ Wout,
                            const float* __restrict__ bout,
                            float* __restrict__ feat) {
    int b = blockIdx.x;
    int tid = threadIdx.x;           // 0..63
    __shared__ float mos[64];
    mos[tid] = w_mo[b * 64 + tid];
    __syncthreads();
    float acc = bout[tid];
    const float4* wr = (const float4*)(Wout + tid * 64);
    #pragma unroll
    for (int d4 = 0; d4 < 16; ++d4) {
        float4 w = wr[d4];
        acc += mos[d4 * 4 + 0] * w.x + mos[d4 * 4 + 1] * w.y
             + mos[d4 * 4 + 2] * w.z + mos[d4 * 4 + 3] * w.w;
    }
    feat[b * NE + tid] = acc;
}

// ---------------------------------------------------------------------------
extern "C" void kernel_launch(void* const* d_in, const int* in_sizes, int n_in,
                              void* d_out, int out_size, void* d_ws, size_t ws_size,
                              hipStream_t stream) {
    const float* eeg      = (const float*)d_in[0];
    const float* gcn1_w   = (const float*)d_in[1];
    const float* gcn1_b   = (const float*)d_in[2];
    const float* gcn2_w   = (const float*)d_in[3];
    const float* gcn2_b   = (const float*)d_in[4];
    const float* bn1_g    = (const float*)d_in[5];
    const float* bn1_b    = (const float*)d_in[6];
    const float* bn2_g    = (const float*)d_in[7];
    const float* bn2_b    = (const float*)d_in[8];
    const float* attn_in_w  = (const float*)d_in[9];
    const float* attn_in_b  = (const float*)d_in[10];
    const float* attn_out_w = (const float*)d_in[11];
    const float* attn_out_b = (const float*)d_in[12];

    float* out  = (float*)d_out;
    float* feat = out;                          // [B, E]
    float* wpli = out + NB * NE;                // [B, C, C]

    float* ws = (float*)d_ws;
    float*  w_re   = ws;                        // [1M]
    float*  w_im   = ws + 1048576;              // [1M]
    float*  w_x1   = ws + 2097152;              // [1M]
    float*  w_x2   = ws + 3145728;              // [512K]
    float*  w_deg  = ws + 3670016;              // [8K]
    float*  w_mo   = ws + 3678208;              // [8K]
    double* dpart1 = (double*)(ws + 3686400);   // [128*64*2]
    double* dpart2 = (double*)(ws + 3719168);   // [128*64*2]

    // 1. analytic signal
    analytic_kernel<<<NB * NC, NT, 0, stream>>>(eeg, w_re, w_im);
    // 2. PLI (+deg), writes wpli output
    pli_kernel<<<NB * NC / 4, 256, 0, stream>>>(w_re, w_im, wpli, w_deg);
    // 3. GCN1 fused, 2 blocks/batch
    gcn_fused<HIDN, false><<<NB * 2, 1024, 0, stream>>>(
        wpli, w_deg, eeg, nullptr, nullptr, nullptr,
        gcn1_w, gcn1_b, w_x1, dpart1);
    // 4. GCN2 fused, 2 blocks/batch
    gcn_fused<NE, true><<<NB * 2, 1024, 0, stream>>>(
        wpli, w_deg, w_x1, dpart1, bn1_g, bn1_b,
        gcn2_w, gcn2_b, w_x2, dpart2);
    // 5. attention per (b, head): 512 blocks
    attn_head<<<NB * NHD, 256, 0, stream>>>(w_x2, dpart2, bn2_g, bn2_b,
                                            attn_in_w, attn_in_b, w_mo);
    // 6. output projection
    proj_kernel<<<NB, NE, 0, stream>>>(w_mo, attn_out_w, attn_out_b, feat);
}

// Round 14
// 91.873 us; speedup vs baseline: 3.1330x; 1.0763x over previous
//
#include <hip/hip_runtime.h>
#include <math.h>

#define NB 128     // batch
#define NC 64      // channels
#define NT 128     // segment length
#define HIDN 128   // hidden
#define NE 64      // attn embed
#define NHD 4      // heads
#define HD 16      // head dim

// ---------------------------------------------------------------------------
// 1. Analytic signal (bit-identical math; [b][c][t] layout).
// ---------------------------------------------------------------------------
__global__ void analytic_kernel(const float* __restrict__ eeg,
                                float* __restrict__ re, float* __restrict__ im) {
    int row = blockIdx.x;            // b*NC + c
    int t = threadIdx.x;             // 0..127
    __shared__ float xs[NT];
    __shared__ double cotv[64];
    xs[t] = eeg[row * NT + t];
    if (t < 64) {
        double d = (double)(2 * t + 1);
        double a = 3.14159265358979323846 * d / 128.0;
        cotv[t] = cos(a) / sin(a);
    }
    __syncthreads();
    double ar = 0.0, ai = 0.0;
    #pragma unroll
    for (int m = 0; m < 64; ++m) {
        int d = 2 * m + 1;
        int s = (t - d) & 127;
        double xv = (double)xs[s];
        ar += xv;
        ai += cotv[m] * xv;
    }
    double rr = (double)xs[t] + ar * (1.0 / 64.0);
    double ii = ai * (1.0 / 64.0);
    re[row * NT + t] = (float)rr;
    im[row * NT + t] = (float)ii;
}

// ---------------------------------------------------------------------------
// 2. PLI v4: 4 blocks/batch (grid 512 = 2 blocks/CU), wave owns 4 i-rows x
//    64 j x full t-sweep -> accumulators finish in registers (no pacc pass).
//    Integer accumulation + identical element expressions + identical deg
//    shuffle order -> wpli bit-identical to v3.
// ---------------------------------------------------------------------------
__global__ void pli_kernel(const float* __restrict__ re, const float* __restrict__ im,
                           float* __restrict__ wpli, float* __restrict__ deg) {
    int b = blockIdx.x >> 2;
    int i0 = (blockIdx.x & 3) << 4;  // 16 i-rows per block
    int tid = threadIdx.x;           // 256
    int iq = tid >> 6;               // wave id 0..3 -> i-quad
    int j = tid & 63;
    __shared__ float4 sre4[64 * 32]; // 32 KB, slot = c*32 + (t4 ^ (c&31))
    __shared__ float4 sim4[64 * 32]; // 32 KB
    const float* reb = re + b * (NC * NT);
    const float* imb = im + b * (NC * NT);
    for (int idx4 = tid; idx4 < 2048; idx4 += 256) {
        int c = idx4 >> 5, t4 = idx4 & 31;
        int slot = c * 32 + (t4 ^ (c & 31));
        sre4[slot] = ((const float4*)reb)[idx4];
        sim4[slot] = ((const float4*)imb)[idx4];
    }
    __syncthreads();
    int ibase = i0 + iq * 4;
    int acc0 = 0, acc1 = 0, acc2 = 0, acc3 = 0;
    #pragma unroll 4
    for (int t4 = 0; t4 < 32; ++t4) {
        float4 rj = sre4[j * 32 + (t4 ^ (j & 31))];
        float4 ij = sim4[j * 32 + (t4 ^ (j & 31))];
        #pragma unroll
        for (int di = 0; di < 4; ++di) {
            int i = ibase + di;
            float4 ri = sre4[i * 32 + (t4 ^ (i & 31))];  // wave-uniform bcast
            float4 ii = sim4[i * 32 + (t4 ^ (i & 31))];
            float c0 = ii.x * rj.x - ri.x * ij.x;
            float c1 = ii.y * rj.y - ri.y * ij.y;
            float c2 = ii.z * rj.z - ri.z * ij.z;
            float c3 = ii.w * rj.w - ri.w * ij.w;
            int d = ((c0 > 0.f) ? 1 : ((c0 < 0.f) ? -1 : 0))
                  + ((c1 > 0.f) ? 1 : ((c1 < 0.f) ? -1 : 0))
                  + ((c2 > 0.f) ? 1 : ((c2 < 0.f) ? -1 : 0))
                  + ((c3 > 0.f) ? 1 : ((c3 < 0.f) ? -1 : 0));
            if (di == 0) acc0 += d;
            else if (di == 1) acc1 += d;
            else if (di == 2) acc2 += d;
            else acc3 += d;
        }
    }
    #pragma unroll
    for (int di = 0; di < 4; ++di) {
        int a = (di == 0) ? acc0 : (di == 1) ? acc1 : (di == 2) ? acc2 : acc3;
        int i = ibase + di;
        float p = fabsf((float)a * (1.f / (float)NT));
        if (j == i) p = 0.f;
        wpli[b * (NC * NC) + i * NC + j] = p;
        float s = p;
        #pragma unroll
        for (int off = 32; off > 0; off >>= 1) s += __shfl_down(s, off);
        if (j == 0) deg[b * NC + i] = s;
    }
}

// ---------------------------------------------------------------------------
// 3. Fused GCN layer, 2 blocks per batch (verified R9/R10/R13).
// ---------------------------------------------------------------------------
template <int OUT, bool BN_IN>
__global__ __launch_bounds__(1024, 1) void gcn_fused(
        const float* __restrict__ adj, const float* __restrict__ deg,
        const float* __restrict__ x, const double* __restrict__ dpart_in,
        const float* __restrict__ g, const float* __restrict__ bb,
        const float* __restrict__ W, const float* __restrict__ bias,
        float* __restrict__ xout, double* __restrict__ dpart_out) {
    int b = blockIdx.x >> 1;
    int half = blockIdx.x & 1;
    int tid = threadIdx.x;           // 1024
    __shared__ float dn_s[64];
    __shared__ float stat_s[64][2];
    __shared__ float arow[32][68];
    __shared__ float xs[64][128];
    __shared__ float sup[32][132];
    __shared__ float WsT[128][(OUT == 128) ? 132 : 68];  // [k][o]
    __shared__ double dred[16][64][2];

    if (BN_IN) {
        int c = tid & 63, chunk = tid >> 6;
        double s = 0.0, s2 = 0.0;
        for (int bi = chunk * 8; bi < chunk * 8 + 8; ++bi) {
            s  += dpart_in[(bi * 64 + c) * 2];
            s2 += dpart_in[(bi * 64 + c) * 2 + 1];
        }
        dred[chunk][c][0] = s;
        dred[chunk][c][1] = s2;
    }
    if (tid < 64)
        dn_s[tid] = (float)(1.0 / sqrt((double)deg[b * 64 + tid] + 1e-8));
    __syncthreads();
    if (BN_IN && tid < 64) {
        double s = 0.0, s2 = 0.0;
        for (int ch = 0; ch < 16; ++ch) {
            s  += dred[ch][tid][0];
            s2 += dred[ch][tid][1];
        }
        double N = (double)(NB * HIDN);
        double m = s / N;
        double var = s2 / N - m * m;
        stat_s[tid][0] = (float)m;
        stat_s[tid][1] = (float)(1.0 / sqrt(var + 1e-5));
    }
    __syncthreads();
    if (tid < 512) {
        int il = tid >> 4, j4 = tid & 15;
        int i = half * 32 + il;
        float4 v = *(const float4*)&adj[b * 4096 + i * 64 + j4 * 4];
        float di = dn_s[i];
        v.x *= di * dn_s[j4 * 4 + 0];
        v.y *= di * dn_s[j4 * 4 + 1];
        v.z *= di * dn_s[j4 * 4 + 2];
        v.w *= di * dn_s[j4 * 4 + 3];
        *(float4*)&arow[il][j4 * 4] = v;
    }
    #pragma unroll
    for (int p = 0; p < 2; ++p) {
        int idx4 = tid + p * 1024;
        int r = idx4 >> 5, c4 = idx4 & 31;
        float4 v = ((const float4*)(x + b * 8192))[idx4];
        if (BN_IN) {
            float m = stat_s[r][0], rs = stat_s[r][1], gg = g[r], bv = bb[r];
            v.x = (v.x - m) * rs * gg + bv; v.x = v.x > 0.f ? v.x : 0.f;
            v.y = (v.y - m) * rs * gg + bv; v.y = v.y > 0.f ? v.y : 0.f;
            v.z = (v.z - m) * rs * gg + bv; v.z = v.z > 0.f ? v.z : 0.f;
            v.w = (v.w - m) * rs * gg + bv; v.w = v.w > 0.f ? v.w : 0.f;
        }
        *(float4*)&xs[r][c4 * 4] = v;
    }
    #pragma unroll
    for (int p = 0; p < OUT / 32; ++p) {
        int idx4 = tid + p * 1024;
        int o = idx4 & (OUT - 1);
        int k4 = idx4 / OUT;
        float4 w = *(const float4*)&W[o * 128 + k4 * 4];
        WsT[k4 * 4 + 0][o] = w.x;
        WsT[k4 * 4 + 1][o] = w.y;
        WsT[k4 * 4 + 2][o] = w.z;
        WsT[k4 * 4 + 3][o] = w.w;
    }
    __syncthreads();

    int il = tid >> 5;
    int i = half * 32 + il;
    {
        int f0 = (tid & 31) * 4;
        float a0 = 0.f, a1 = 0.f, a2 = 0.f, a3 = 0.f;
        #pragma unroll 8
        for (int j = 0; j < 64; ++j) {
            float a = arow[il][j];
            float4 xv = *(const float4*)&xs[j][f0];
            a0 += a * xv.x; a1 += a * xv.y; a2 += a * xv.z; a3 += a * xv.w;
        }
        *(float4*)&sup[il][f0] = make_float4(a0, a1, a2, a3);
    }
    __syncthreads();

    double ds = 0.0, ds2 = 0.0;
    if (OUT == 128) {
        int o0 = (tid & 31) * 4;
        float c[4] = {};
        #pragma unroll 8
        for (int k = 0; k < 128; ++k) {
            float s = sup[il][k];
            float4 w0 = *(const float4*)&WsT[k][o0];
            c[0] += s * w0.x; c[1] += s * w0.y; c[2] += s * w0.z; c[3] += s * w0.w;
        }
        float4 r0 = make_float4(c[0] + bias[o0], c[1] + bias[o0 + 1],
                                c[2] + bias[o0 + 2], c[3] + bias[o0 + 3]);
        *(float4*)&xout[b * 64 * 128 + i * 128 + o0] = r0;
        ds  = (double)r0.x + (double)r0.y + (double)r0.z + (double)r0.w;
        ds2 = (double)r0.x * r0.x + (double)r0.y * r0.y
            + (double)r0.z * r0.z + (double)r0.w * r0.w;
    } else {
        int o0 = (tid & 31) * 2;
        float c0 = 0.f, c1 = 0.f;
        #pragma unroll 8
        for (int k = 0; k < 128; ++k) {
            float s = sup[il][k];
            c0 += s * WsT[k][o0];
            c1 += s * WsT[k][o0 + 1];
        }
        c0 += bias[o0];
        c1 += bias[o0 + 1];
        *(float2*)&xout[b * 64 * 64 + i * 64 + o0] = make_float2(c0, c1);
        ds  = (double)c0 + (double)c1;
        ds2 = (double)c0 * c0 + (double)c1 * c1;
    }
    #pragma unroll
    for (int off = 16; off > 0; off >>= 1) {
        ds  += __shfl_down(ds, off, 32);
        ds2 += __shfl_down(ds2, off, 32);
    }
    if ((tid & 31) == 0) {
        dpart_out[(b * 64 + i) * 2]     = ds;
        dpart_out[(b * 64 + i) * 2 + 1] = ds2;
    }
}

// ---------------------------------------------------------------------------
// 4. Attention per (b, head), 256 threads (verified R10/R13).
// ---------------------------------------------------------------------------
__global__ __launch_bounds__(256) void attn_head(
        const float* __restrict__ x2, const double* __restrict__ dpart2,
        const float* __restrict__ g, const float* __restrict__ bb,
        const float* __restrict__ Win, const float* __restrict__ bin,
        float* __restrict__ w_mo) {
    int b = blockIdx.x >> 2, h = blockIdx.x & 3;
    int tid = threadIdx.x;
    int lane = tid & 63, wv = tid >> 6;
    __shared__ double dred[4][64][2];
    __shared__ float stat_s[64][2];
    __shared__ float xs[64][68];
    __shared__ float ws[48][64];
    __shared__ float kqkv[48][64];
    __shared__ float pm_s[4][64], ps_s[4][64];
    __shared__ float pool_s[16][17];

    {
        double s = 0.0, s2 = 0.0;
        for (int bi = wv * 32; bi < wv * 32 + 32; ++bi) {
            s  += dpart2[(bi * 64 + lane) * 2];
            s2 += dpart2[(bi * 64 + lane) * 2 + 1];
        }
        dred[wv][lane][0] = s;
        dred[wv][lane][1] = s2;
    }
    __syncthreads();
    if (tid < 64) {
        double s  = dred[0][tid][0] + dred[1][tid][0] + dred[2][tid][0] + dred[3][tid][0];
        double s2 = dred[0][tid][1] + dred[1][tid][1] + dred[2][tid][1] + dred[3][tid][1];
        double N = (double)(NB * NE);
        double m = s / N;
        double var = s2 / N - m * m;
        stat_s[tid][0] = (float)m;
        stat_s[tid][1] = (float)(1.0 / sqrt(var + 1e-5));
    }
    __syncthreads();
    for (int idx4 = tid; idx4 < 1024; idx4 += 256) {
        int r = idx4 >> 4, c4 = idx4 & 15;
        float4 v = ((const float4*)(x2 + b * 4096))[idx4];
        float m = stat_s[r][0], rs = stat_s[r][1], gg = g[r], bv = bb[r];
        v.x = (v.x - m) * rs * gg + bv; v.x = v.x > 0.f ? v.x : 0.f;
        v.y = (v.y - m) * rs * gg + bv; v.y = v.y > 0.f ? v.y : 0.f;
        v.z = (v.z - m) * rs * gg + bv; v.z = v.z > 0.f ? v.z : 0.f;
        v.w = (v.w - m) * rs * gg + bv; v.w = v.w > 0.f ? v.w : 0.f;
        *(float4*)&xs[r][c4 * 4] = v;
    }
    for (int idx4 = tid; idx4 < 768; idx4 += 256) {
        int rl = idx4 >> 4, c4 = idx4 & 15;
        int rg = ((rl >> 4) << 6) + (h << 4) + (rl & 15);
        *(float4*)&ws[rl][c4 * 4] = ((const float4*)(Win + rg * 64))[c4];
    }
    __syncthreads();

    float acc[12];
    #pragma unroll
    for (int u = 0; u < 12; ++u) {
        int ol = wv + 4 * u;
        acc[u] = bin[((ol >> 4) << 6) + (h << 4) + (ol & 15)];
    }
    #pragma unroll
    for (int d4 = 0; d4 < 16; ++d4) {
        float4 xv = *(const float4*)&xs[lane][d4 * 4];
        #pragma unroll
        for (int u = 0; u < 12; ++u) {
            float4 w = *(const float4*)&ws[wv + 4 * u][d4 * 4];
            acc[u] += xv.x * w.x + xv.y * w.y + xv.z * w.z + xv.w * w.w;
        }
    }
    #pragma unroll
    for (int u = 0; u < 12; ++u) kqkv[wv + 4 * u][lane] = acc[u];
    __syncthreads();

    int j0 = wv * 16;
    float q[16];
    #pragma unroll
    for (int d = 0; d < 16; ++d) q[d] = kqkv[d][lane];
    float sc[16];
    #pragma unroll
    for (int jj = 0; jj < 16; ++jj) sc[jj] = 0.f;
    #pragma unroll
    for (int d = 0; d < 16; ++d) {
        float qd = q[d];
        #pragma unroll
        for (int j4 = 0; j4 < 4; ++j4) {
            float4 kv = *(const float4*)&kqkv[16 + d][j0 + j4 * 4];
            sc[j4 * 4 + 0] += qd * kv.x;
            sc[j4 * 4 + 1] += qd * kv.y;
            sc[j4 * 4 + 2] += qd * kv.z;
            sc[j4 * 4 + 3] += qd * kv.w;
        }
    }
    float pmax = -1e30f;
    #pragma unroll
    for (int jj = 0; jj < 16; ++jj) { sc[jj] *= 0.25f; pmax = fmaxf(pmax, sc[jj]); }
    pm_s[wv][lane] = pmax;
    __syncthreads();
    float mx = fmaxf(fmaxf(pm_s[0][lane], pm_s[1][lane]),
                     fmaxf(pm_s[2][lane], pm_s[3][lane]));
    float psum = 0.f;
    #pragma unroll
    for (int jj = 0; jj < 16; ++jj) { sc[jj] = expf(sc[jj] - mx); psum += sc[jj]; }
    ps_s[wv][lane] = psum;
    float po[16];
    #pragma unroll
    for (int d = 0; d < 16; ++d) {
        float4 v0 = *(const float4*)&kqkv[32 + d][j0 + 0];
        float4 v1 = *(const float4*)&kqkv[32 + d][j0 + 4];
        float4 v2 = *(const float4*)&kqkv[32 + d][j0 + 8];
        float4 v3 = *(const float4*)&kqkv[32 + d][j0 + 12];
        po[d] = sc[0] * v0.x + sc[1] * v0.y + sc[2] * v0.z + sc[3] * v0.w
              + sc[4] * v1.x + sc[5] * v1.y + sc[6] * v1.z + sc[7] * v1.w
              + sc[8] * v2.x + sc[9] * v2.y + sc[10] * v2.z + sc[11] * v2.w
              + sc[12] * v3.x + sc[13] * v3.y + sc[14] * v3.z + sc[15] * v3.w;
    }
    __syncthreads();
    float inv = 1.f / (ps_s[0][lane] + ps_s[1][lane] + ps_s[2][lane] + ps_s[3][lane]);
    if (wv == 0) {
        #pragma unroll
        for (int d = 0; d < 16; ++d) kqkv[d][lane] = po[d];
    }
    __syncthreads();
    if (wv == 1) {
        #pragma unroll
        for (int d = 0; d < 16; ++d) kqkv[d][lane] += po[d];
    }
    __syncthreads();
    if (wv == 2) {
        #pragma unroll
        for (int d = 0; d < 16; ++d) kqkv[d][lane] += po[d];
    }
    __syncthreads();
    if (wv == 3) {
        #pragma unroll
        for (int d = 0; d < 16; ++d)
            kqkv[d][lane] = (kqkv[d][lane] + po[d]) * inv;
    }
    __syncthreads();
    {
        int d = tid & 15, part = tid >> 4;
        float4 v = *(const float4*)&kqkv[d][part * 4];
        pool_s[d][part] = v.x + v.y + v.z + v.w;
    }
    __syncthreads();
    if (tid < 16) {
        float s = 0.f;
        #pragma unroll
        for (int p = 0; p < 16; ++p) s += pool_s[tid][p];
        w_mo[b * 64 + h * 16 + tid] = s * (1.f / 64.f);
    }
}

// ---------------------------------------------------------------------------
// 5. Output projection: feat[b][e] = bout[e] + sum_d Wout[e][d] * mo[b][d]
// ---------------------------------------------------------------------------
__global__ void proj_kernel(const float* __restrict__ w_mo,
                            const float* __restrict__ Wout,
                            const float* __restrict__ bout,
                            float* __restrict__ feat) {
    int b = blockIdx.x;
    int tid = threadIdx.x;           // 0..63
    __shared__ float mos[64];
    mos[tid] = w_mo[b * 64 + tid];
    __syncthreads();
    float acc = bout[tid];
    const float4* wr = (const float4*)(Wout + tid * 64);
    #pragma unroll
    for (int d4 = 0; d4 < 16; ++d4) {
        float4 w = wr[d4];
        acc += mos[d4 * 4 + 0] * w.x + mos[d4 * 4 + 1] * w.y
             + mos[d4 * 4 + 2] * w.z + mos[d4 * 4 + 3] * w.w;
    }
    feat[b * NE + tid] = acc;
}

// ---------------------------------------------------------------------------
extern "C" void kernel_launch(void* const* d_in, const int* in_sizes, int n_in,
                              void* d_out, int out_size, void* d_ws, size_t ws_size,
                              hipStream_t stream) {
    const float* eeg      = (const float*)d_in[0];
    const float* gcn1_w   = (const float*)d_in[1];
    const float* gcn1_b   = (const float*)d_in[2];
    const float* gcn2_w   = (const float*)d_in[3];
    const float* gcn2_b   = (const float*)d_in[4];
    const float* bn1_g    = (const float*)d_in[5];
    const float* bn1_b    = (const float*)d_in[6];
    const float* bn2_g    = (const float*)d_in[7];
    const float* bn2_b    = (const float*)d_in[8];
    const float* attn_in_w  = (const float*)d_in[9];
    const float* attn_in_b  = (const float*)d_in[10];
    const float* attn_out_w = (const float*)d_in[11];
    const float* attn_out_b = (const float*)d_in[12];

    float* out  = (float*)d_out;
    float* feat = out;                          // [B, E]
    float* wpli = out + NB * NE;                // [B, C, C]

    float* ws = (float*)d_ws;
    float*  w_re   = ws;                        // [1M]
    float*  w_im   = ws + 1048576;              // [1M]
    float*  w_x1   = ws + 2097152;              // [1M]
    float*  w_x2   = ws + 3145728;              // [512K]
    float*  w_deg  = ws + 3670016;              // [8K]
    float*  w_mo   = ws + 3678208;              // [8K]
    double* dpart1 = (double*)(ws + 3686400);   // [128*64*2]
    double* dpart2 = (double*)(ws + 3719168);   // [128*64*2]

    // 1. analytic signal
    analytic_kernel<<<NB * NC, NT, 0, stream>>>(eeg, w_re, w_im);
    // 2. PLI v4 (+deg), writes wpli output (4 blocks/batch)
    pli_kernel<<<NB * 4, 256, 0, stream>>>(w_re, w_im, wpli, w_deg);
    // 3. GCN1 fused, 2 blocks/batch
    gcn_fused<HIDN, false><<<NB * 2, 1024, 0, stream>>>(
        wpli, w_deg, eeg, nullptr, nullptr, nullptr,
        gcn1_w, gcn1_b, w_x1, dpart1);
    // 4. GCN2 fused, 2 blocks/batch
    gcn_fused<NE, true><<<NB * 2, 1024, 0, stream>>>(
        wpli, w_deg, w_x1, dpart1, bn1_g, bn1_b,
        gcn2_w, gcn2_b, w_x2, dpart2);
    // 5. attention per (b, head): 512 blocks
    attn_head<<<NB * NHD, 256, 0, stream>>>(w_x2, dpart2, bn2_g, bn2_b,
                                            attn_in_w, attn_in_b, w_mo);
    // 6. output projection
    proj_kernel<<<NB, NE, 0, stream>>>(w_mo, attn_out_w, attn_out_b, feat);
}

// Round 15
// 89.517 us; speedup vs baseline: 3.2155x; 1.0263x over previous
//
#include <hip/hip_runtime.h>
#include <math.h>

#define NB 128     // batch
#define NC 64      // channels
#define NT 128     // segment length
#define HIDN 128   // hidden
#define NE 64      // attn embed
#define NHD 4      // heads
#define HD 16      // head dim

// ---------------------------------------------------------------------------
// 1. Analytic signal v2: 8 rows per block (1024 blocks x 1024 threads).
//    cot table computed ONCE per block (was: once per row-block = 8x more
//    double transcendentals). Per-(row,t) math verbatim -> bit-identical.
// ---------------------------------------------------------------------------
__global__ __launch_bounds__(1024) void analytic_kernel(
        const float* __restrict__ eeg,
        float* __restrict__ re, float* __restrict__ im) {
    int row0 = blockIdx.x * 8;       // 1024 blocks
    int tid = threadIdx.x;
    int r = tid >> 7, t = tid & 127;
    int row = row0 + r;
    __shared__ float xs[8][128];
    __shared__ double cotv[64];
    xs[r][t] = eeg[row * NT + t];
    if (tid < 64) {
        double d = (double)(2 * tid + 1);
        double a = 3.14159265358979323846 * d / 128.0;
        cotv[tid] = cos(a) / sin(a);
    }
    __syncthreads();
    double ar = 0.0, ai = 0.0;
    #pragma unroll
    for (int m = 0; m < 64; ++m) {
        int d = 2 * m + 1;
        int s = (t - d) & 127;
        double xv = (double)xs[r][s];
        ar += xv;
        ai += cotv[m] * xv;
    }
    double rr = (double)xs[r][t] + ar * (1.0 / 64.0);
    double ii = ai * (1.0 / 64.0);
    re[row * NT + t] = (float)rr;
    im[row * NT + t] = (float)ii;
}

// ---------------------------------------------------------------------------
// 2. PLI v4 (verified R14): 4 blocks/batch, register accumulators.
// ---------------------------------------------------------------------------
__global__ void pli_kernel(const float* __restrict__ re, const float* __restrict__ im,
                           float* __restrict__ wpli, float* __restrict__ deg) {
    int b = blockIdx.x >> 2;
    int i0 = (blockIdx.x & 3) << 4;  // 16 i-rows per block
    int tid = threadIdx.x;           // 256
    int iq = tid >> 6;               // wave id 0..3 -> i-quad
    int j = tid & 63;
    __shared__ float4 sre4[64 * 32]; // 32 KB, slot = c*32 + (t4 ^ (c&31))
    __shared__ float4 sim4[64 * 32]; // 32 KB
    const float* reb = re + b * (NC * NT);
    const float* imb = im + b * (NC * NT);
    for (int idx4 = tid; idx4 < 2048; idx4 += 256) {
        int c = idx4 >> 5, t4 = idx4 & 31;
        int slot = c * 32 + (t4 ^ (c & 31));
        sre4[slot] = ((const float4*)reb)[idx4];
        sim4[slot] = ((const float4*)imb)[idx4];
    }
    __syncthreads();
    int ibase = i0 + iq * 4;
    int acc0 = 0, acc1 = 0, acc2 = 0, acc3 = 0;
    #pragma unroll 4
    for (int t4 = 0; t4 < 32; ++t4) {
        float4 rj = sre4[j * 32 + (t4 ^ (j & 31))];
        float4 ij = sim4[j * 32 + (t4 ^ (j & 31))];
        #pragma unroll
        for (int di = 0; di < 4; ++di) {
            int i = ibase + di;
            float4 ri = sre4[i * 32 + (t4 ^ (i & 31))];  // wave-uniform bcast
            float4 ii = sim4[i * 32 + (t4 ^ (i & 31))];
            float c0 = ii.x * rj.x - ri.x * ij.x;
            float c1 = ii.y * rj.y - ri.y * ij.y;
            float c2 = ii.z * rj.z - ri.z * ij.z;
            float c3 = ii.w * rj.w - ri.w * ij.w;
            int d = ((c0 > 0.f) ? 1 : ((c0 < 0.f) ? -1 : 0))
                  + ((c1 > 0.f) ? 1 : ((c1 < 0.f) ? -1 : 0))
                  + ((c2 > 0.f) ? 1 : ((c2 < 0.f) ? -1 : 0))
                  + ((c3 > 0.f) ? 1 : ((c3 < 0.f) ? -1 : 0));
            if (di == 0) acc0 += d;
            else if (di == 1) acc1 += d;
            else if (di == 2) acc2 += d;
            else acc3 += d;
        }
    }
    #pragma unroll
    for (int di = 0; di < 4; ++di) {
        int a = (di == 0) ? acc0 : (di == 1) ? acc1 : (di == 2) ? acc2 : acc3;
        int i = ibase + di;
        float p = fabsf((float)a * (1.f / (float)NT));
        if (j == i) p = 0.f;
        wpli[b * (NC * NC) + i * NC + j] = p;
        float s = p;
        #pragma unroll
        for (int off = 32; off > 0; off >>= 1) s += __shfl_down(s, off);
        if (j == 0) deg[b * NC + i] = s;
    }
}

// ---------------------------------------------------------------------------
// 3. Fused GCN layer, 2 blocks per batch (verified R9/R10/R13/R14).
// ---------------------------------------------------------------------------
template <int OUT, bool BN_IN>
__global__ __launch_bounds__(1024, 1) void gcn_fused(
        const float* __restrict__ adj, const float* __restrict__ deg,
        const float* __restrict__ x, const double* __restrict__ dpart_in,
        const float* __restrict__ g, const float* __restrict__ bb,
        const float* __restrict__ W, const float* __restrict__ bias,
        float* __restrict__ xout, double* __restrict__ dpart_out) {
    int b = blockIdx.x >> 1;
    int half = blockIdx.x & 1;
    int tid = threadIdx.x;           // 1024
    __shared__ float dn_s[64];
    __shared__ float stat_s[64][2];
    __shared__ float arow[32][68];
    __shared__ float xs[64][128];
    __shared__ float sup[32][132];
    __shared__ float WsT[128][(OUT == 128) ? 132 : 68];  // [k][o]
    __shared__ double dred[16][64][2];

    if (BN_IN) {
        int c = tid & 63, chunk = tid >> 6;
        double s = 0.0, s2 = 0.0;
        for (int bi = chunk * 8; bi < chunk * 8 + 8; ++bi) {
            s  += dpart_in[(bi * 64 + c) * 2];
            s2 += dpart_in[(bi * 64 + c) * 2 + 1];
        }
        dred[chunk][c][0] = s;
        dred[chunk][c][1] = s2;
    }
    if (tid < 64)
        dn_s[tid] = (float)(1.0 / sqrt((double)deg[b * 64 + tid] + 1e-8));
    __syncthreads();
    if (BN_IN && tid < 64) {
        double s = 0.0, s2 = 0.0;
        for (int ch = 0; ch < 16; ++ch) {
            s  += dred[ch][tid][0];
            s2 += dred[ch][tid][1];
        }
        double N = (double)(NB * HIDN);
        double m = s / N;
        double var = s2 / N - m * m;
        stat_s[tid][0] = (float)m;
        stat_s[tid][1] = (float)(1.0 / sqrt(var + 1e-5));
    }
    __syncthreads();
    if (tid < 512) {
        int il = tid >> 4, j4 = tid & 15;
        int i = half * 32 + il;
        float4 v = *(const float4*)&adj[b * 4096 + i * 64 + j4 * 4];
        float di = dn_s[i];
        v.x *= di * dn_s[j4 * 4 + 0];
        v.y *= di * dn_s[j4 * 4 + 1];
        v.z *= di * dn_s[j4 * 4 + 2];
        v.w *= di * dn_s[j4 * 4 + 3];
        *(float4*)&arow[il][j4 * 4] = v;
    }
    #pragma unroll
    for (int p = 0; p < 2; ++p) {
        int idx4 = tid + p * 1024;
        int r = idx4 >> 5, c4 = idx4 & 31;
        float4 v = ((const float4*)(x + b * 8192))[idx4];
        if (BN_IN) {
            float m = stat_s[r][0], rs = stat_s[r][1], gg = g[r], bv = bb[r];
            v.x = (v.x - m) * rs * gg + bv; v.x = v.x > 0.f ? v.x : 0.f;
            v.y = (v.y - m) * rs * gg + bv; v.y = v.y > 0.f ? v.y : 0.f;
            v.z = (v.z - m) * rs * gg + bv; v.z = v.z > 0.f ? v.z : 0.f;
            v.w = (v.w - m) * rs * gg + bv; v.w = v.w > 0.f ? v.w : 0.f;
        }
        *(float4*)&xs[r][c4 * 4] = v;
    }
    #pragma unroll
    for (int p = 0; p < OUT / 32; ++p) {
        int idx4 = tid + p * 1024;
        int o = idx4 & (OUT - 1);
        int k4 = idx4 / OUT;
        float4 w = *(const float4*)&W[o * 128 + k4 * 4];
        WsT[k4 * 4 + 0][o] = w.x;
        WsT[k4 * 4 + 1][o] = w.y;
        WsT[k4 * 4 + 2][o] = w.z;
        WsT[k4 * 4 + 3][o] = w.w;
    }
    __syncthreads();

    int il = tid >> 5;
    int i = half * 32 + il;
    {
        int f0 = (tid & 31) * 4;
        float a0 = 0.f, a1 = 0.f, a2 = 0.f, a3 = 0.f;
        #pragma unroll 8
        for (int j = 0; j < 64; ++j) {
            float a = arow[il][j];
            float4 xv = *(const float4*)&xs[j][f0];
            a0 += a * xv.x; a1 += a * xv.y; a2 += a * xv.z; a3 += a * xv.w;
        }
        *(float4*)&sup[il][f0] = make_float4(a0, a1, a2, a3);
    }
    __syncthreads();

    double ds = 0.0, ds2 = 0.0;
    if (OUT == 128) {
        int o0 = (tid & 31) * 4;
        float c[4] = {};
        #pragma unroll 8
        for (int k = 0; k < 128; ++k) {
            float s = sup[il][k];
            float4 w0 = *(const float4*)&WsT[k][o0];
            c[0] += s * w0.x; c[1] += s * w0.y; c[2] += s * w0.z; c[3] += s * w0.w;
        }
        float4 r0 = make_float4(c[0] + bias[o0], c[1] + bias[o0 + 1],
                                c[2] + bias[o0 + 2], c[3] + bias[o0 + 3]);
        *(float4*)&xout[b * 64 * 128 + i * 128 + o0] = r0;
        ds  = (double)r0.x + (double)r0.y + (double)r0.z + (double)r0.w;
        ds2 = (double)r0.x * r0.x + (double)r0.y * r0.y
            + (double)r0.z * r0.z + (double)r0.w * r0.w;
    } else {
        int o0 = (tid & 31) * 2;
        float c0 = 0.f, c1 = 0.f;
        #pragma unroll 8
        for (int k = 0; k < 128; ++k) {
            float s = sup[il][k];
            c0 += s * WsT[k][o0];
            c1 += s * WsT[k][o0 + 1];
        }
        c0 += bias[o0];
        c1 += bias[o0 + 1];
        *(float2*)&xout[b * 64 * 64 + i * 64 + o0] = make_float2(c0, c1);
        ds  = (double)c0 + (double)c1;
        ds2 = (double)c0 * c0 + (double)c1 * c1;
    }
    #pragma unroll
    for (int off = 16; off > 0; off >>= 1) {
        ds  += __shfl_down(ds, off, 32);
        ds2 += __shfl_down(ds2, off, 32);
    }
    if ((tid & 31) == 0) {
        dpart_out[(b * 64 + i) * 2]     = ds;
        dpart_out[(b * 64 + i) * 2 + 1] = ds2;
    }
}

// ---------------------------------------------------------------------------
// 4. Attention per (b, head), 256 threads (verified R10/R13/R14).
// ---------------------------------------------------------------------------
__global__ __launch_bounds__(256) void attn_head(
        const float* __restrict__ x2, const double* __restrict__ dpart2,
        const float* __restrict__ g, const float* __restrict__ bb,
        const float* __restrict__ Win, const float* __restrict__ bin,
        float* __restrict__ w_mo) {
    int b = blockIdx.x >> 2, h = blockIdx.x & 3;
    int tid = threadIdx.x;
    int lane = tid & 63, wv = tid >> 6;
    __shared__ double dred[4][64][2];
    __shared__ float stat_s[64][2];
    __shared__ float xs[64][68];
    __shared__ float ws[48][64];
    __shared__ float kqkv[48][64];
    __shared__ float pm_s[4][64], ps_s[4][64];
    __shared__ float pool_s[16][17];

    {
        double s = 0.0, s2 = 0.0;
        for (int bi = wv * 32; bi < wv * 32 + 32; ++bi) {
            s  += dpart2[(bi * 64 + lane) * 2];
            s2 += dpart2[(bi * 64 + lane) * 2 + 1];
        }
        dred[wv][lane][0] = s;
        dred[wv][lane][1] = s2;
    }
    __syncthreads();
    if (tid < 64) {
        double s  = dred[0][tid][0] + dred[1][tid][0] + dred[2][tid][0] + dred[3][tid][0];
        double s2 = dred[0][tid][1] + dred[1][tid][1] + dred[2][tid][1] + dred[3][tid][1];
        double N = (double)(NB * NE);
        double m = s / N;
        double var = s2 / N - m * m;
        stat_s[tid][0] = (float)m;
        stat_s[tid][1] = (float)(1.0 / sqrt(var + 1e-5));
    }
    __syncthreads();
    for (int idx4 = tid; idx4 < 1024; idx4 += 256) {
        int r = idx4 >> 4, c4 = idx4 & 15;
        float4 v = ((const float4*)(x2 + b * 4096))[idx4];
        float m = stat_s[r][0], rs = stat_s[r][1], gg = g[r], bv = bb[r];
        v.x = (v.x - m) * rs * gg + bv; v.x = v.x > 0.f ? v.x : 0.f;
        v.y = (v.y - m) * rs * gg + bv; v.y = v.y > 0.f ? v.y : 0.f;
        v.z = (v.z - m) * rs * gg + bv; v.z = v.z > 0.f ? v.z : 0.f;
        v.w = (v.w - m) * rs * gg + bv; v.w = v.w > 0.f ? v.w : 0.f;
        *(float4*)&xs[r][c4 * 4] = v;
    }
    for (int idx4 = tid; idx4 < 768; idx4 += 256) {
        int rl = idx4 >> 4, c4 = idx4 & 15;
        int rg = ((rl >> 4) << 6) + (h << 4) + (rl & 15);
        *(float4*)&ws[rl][c4 * 4] = ((const float4*)(Win + rg * 64))[c4];
    }
    __syncthreads();

    float acc[12];
    #pragma unroll
    for (int u = 0; u < 12; ++u) {
        int ol = wv + 4 * u;
        acc[u] = bin[((ol >> 4) << 6) + (h << 4) + (ol & 15)];
    }
    #pragma unroll
    for (int d4 = 0; d4 < 16; ++d4) {
        float4 xv = *(const float4*)&xs[lane][d4 * 4];
        #pragma unroll
        for (int u = 0; u < 12; ++u) {
            float4 w = *(const float4*)&ws[wv + 4 * u][d4 * 4];
            acc[u] += xv.x * w.x + xv.y * w.y + xv.z * w.z + xv.w * w.w;
        }
    }
    #pragma unroll
    for (int u = 0; u < 12; ++u) kqkv[wv + 4 * u][lane] = acc[u];
    __syncthreads();

    int j0 = wv * 16;
    float q[16];
    #pragma unroll
    for (int d = 0; d < 16; ++d) q[d] = kqkv[d][lane];
    float sc[16];
    #pragma unroll
    for (int jj = 0; jj < 16; ++jj) sc[jj] = 0.f;
    #pragma unroll
    for (int d = 0; d < 16; ++d) {
        float qd = q[d];
        #pragma unroll
        for (int j4 = 0; j4 < 4; ++j4) {
            float4 kv = *(const float4*)&kqkv[16 + d][j0 + j4 * 4];
            sc[j4 * 4 + 0] += qd * kv.x;
            sc[j4 * 4 + 1] += qd * kv.y;
            sc[j4 * 4 + 2] += qd * kv.z;
            sc[j4 * 4 + 3] += qd * kv.w;
        }
    }
    float pmax = -1e30f;
    #pragma unroll
    for (int jj = 0; jj < 16; ++jj) { sc[jj] *= 0.25f; pmax = fmaxf(pmax, sc[jj]); }
    pm_s[wv][lane] = pmax;
    __syncthreads();
    float mx = fmaxf(fmaxf(pm_s[0][lane], pm_s[1][lane]),
                     fmaxf(pm_s[2][lane], pm_s[3][lane]));
    float psum = 0.f;
    #pragma unroll
    for (int jj = 0; jj < 16; ++jj) { sc[jj] = expf(sc[jj] - mx); psum += sc[jj]; }
    ps_s[wv][lane] = psum;
    float po[16];
    #pragma unroll
    for (int d = 0; d < 16; ++d) {
        float4 v0 = *(const float4*)&kqkv[32 + d][j0 + 0];
        float4 v1 = *(const float4*)&kqkv[32 + d][j0 + 4];
        float4 v2 = *(const float4*)&kqkv[32 + d][j0 + 8];
        float4 v3 = *(const float4*)&kqkv[32 + d][j0 + 12];
        po[d] = sc[0] * v0.x + sc[1] * v0.y + sc[2] * v0.z + sc[3] * v0.w
              + sc[4] * v1.x + sc[5] * v1.y + sc[6] * v1.z + sc[7] * v1.w
              + sc[8] * v2.x + sc[9] * v2.y + sc[10] * v2.z + sc[11] * v2.w
              + sc[12] * v3.x + sc[13] * v3.y + sc[14] * v3.z + sc[15] * v3.w;
    }
    __syncthreads();
    float inv = 1.f / (ps_s[0][lane] + ps_s[1][lane] + ps_s[2][lane] + ps_s[3][lane]);
    if (wv == 0) {
        #pragma unroll
        for (int d = 0; d < 16; ++d) kqkv[d][lane] = po[d];
    }
    __syncthreads();
    if (wv == 1) {
        #pragma unroll
        for (int d = 0; d < 16; ++d) kqkv[d][lane] += po[d];
    }
    __syncthreads();
    if (wv == 2) {
        #pragma unroll
        for (int d = 0; d < 16; ++d) kqkv[d][lane] += po[d];
    }
    __syncthreads();
    if (wv == 3) {
        #pragma unroll
        for (int d = 0; d < 16; ++d)
            kqkv[d][lane] = (kqkv[d][lane] + po[d]) * inv;
    }
    __syncthreads();
    {
        int d = tid & 15, part = tid >> 4;
        float4 v = *(const float4*)&kqkv[d][part * 4];
        pool_s[d][part] = v.x + v.y + v.z + v.w;
    }
    __syncthreads();
    if (tid < 16) {
        float s = 0.f;
        #pragma unroll
        for (int p = 0; p < 16; ++p) s += pool_s[tid][p];
        w_mo[b * 64 + h * 16 + tid] = s * (1.f / 64.f);
    }
}

// ---------------------------------------------------------------------------
// 5. Output projection: feat[b][e] = bout[e] + sum_d Wout[e][d] * mo[b][d]
// ---------------------------------------------------------------------------
__global__ void proj_kernel(const float* __restrict__ w_mo,
                            const float* __restrict__ Wout,
                            const float* __restrict__ bout,
                            float* __restrict__ feat) {
    int b = blockIdx.x;
    int tid = threadIdx.x;           // 0..63
    __shared__ float mos[64];
    mos[tid] = w_mo[b * 64 + tid];
    __syncthreads();
    float acc = bout[tid];
    const float4* wr = (const float4*)(Wout + tid * 64);
    #pragma unroll
    for (int d4 = 0; d4 < 16; ++d4) {
        float4 w = wr[d4];
        acc += mos[d4 * 4 + 0] * w.x + mos[d4 * 4 + 1] * w.y
             + mos[d4 * 4 + 2] * w.z + mos[d4 * 4 + 3] * w.w;
    }
    feat[b * NE + tid] = acc;
}

// ---------------------------------------------------------------------------
extern "C" void kernel_launch(void* const* d_in, const int* in_sizes, int n_in,
                              void* d_out, int out_size, void* d_ws, size_t ws_size,
                              hipStream_t stream) {
    const float* eeg      = (const float*)d_in[0];
    const float* gcn1_w   = (const float*)d_in[1];
    const float* gcn1_b   = (const float*)d_in[2];
    const float* gcn2_w   = (const float*)d_in[3];
    const float* gcn2_b   = (const float*)d_in[4];
    const float* bn1_g    = (const float*)d_in[5];
    const float* bn1_b    = (const float*)d_in[6];
    const float* bn2_g    = (const float*)d_in[7];
    const float* bn2_b    = (const float*)d_in[8];
    const float* attn_in_w  = (const float*)d_in[9];
    const float* attn_in_b  = (const float*)d_in[10];
    const float* attn_out_w = (const float*)d_in[11];
    const float* attn_out_b = (const float*)d_in[12];

    float* out  = (float*)d_out;
    float* feat = out;                          // [B, E]
    float* wpli = out + NB * NE;                // [B, C, C]

    float* ws = (float*)d_ws;
    float*  w_re   = ws;                        // [1M]
    float*  w_im   = ws + 1048576;              // [1M]
    float*  w_x1   = ws + 2097152;              // [1M]
    float*  w_x2   = ws + 3145728;              // [512K]
    float*  w_deg  = ws + 3670016;              // [8K]
    float*  w_mo   = ws + 3678208;              // [8K]
    double* dpart1 = (double*)(ws + 3686400);   // [128*64*2]
    double* dpart2 = (double*)(ws + 3719168);   // [128*64*2]

    // 1. analytic signal v2 (8 rows/block)
    analytic_kernel<<<NB * NC / 8, 1024, 0, stream>>>(eeg, w_re, w_im);
    // 2. PLI v4 (+deg), writes wpli output (4 blocks/batch)
    pli_kernel<<<NB * 4, 256, 0, stream>>>(w_re, w_im, wpli, w_deg);
    // 3. GCN1 fused, 2 blocks/batch
    gcn_fused<HIDN, false><<<NB * 2, 1024, 0, stream>>>(
        wpli, w_deg, eeg, nullptr, nullptr, nullptr,
        gcn1_w, gcn1_b, w_x1, dpart1);
    // 4. GCN2 fused, 2 blocks/batch
    gcn_fused<NE, true><<<NB * 2, 1024, 0, stream>>>(
        wpli, w_deg, w_x1, dpart1, bn1_g, bn1_b,
        gcn2_w, gcn2_b, w_x2, dpart2);
    // 5. attention per (b, head): 512 blocks
    attn_head<<<NB * NHD, 256, 0, stream>>>(w_x2, dpart2, bn2_g, bn2_b,
                                            attn_in_w, attn_in_b, w_mo);
    // 6. output projection
    proj_kernel<<<NB, NE, 0, stream>>>(w_mo, attn_out_w, attn_out_b, feat);
}